// Round 12
// baseline (2275.304 us; speedup 1.0000x reference)
//
#include <hip/hip_runtime.h>
#include <math.h>

// Problem dims
constexpr int B_  = 4;
constexpr int T_  = 16;
constexpr int CIN = 32;
constexpr int HID = 64;
constexpr int HH  = 64;
constexpr int WW  = 64;
constexpr int HW  = HH * WW; // 4096

// ---------------- MFMA path config ----------------
constexpr int TR = 8,  TC = 16;         // output pixel tile: 8 rows x 16 cols
constexpr int PR = TR + 2, PC = TC + 2; // 10 x 18 (halo)
constexpr int CSL = 40;                 // channel slots per pixel (80B)
constexpr int KCH = 32;                 // channels per K-chunk
constexpr int ASLAB_HW  = 3 * 36 * 16 * 8;            // 13824 hw (27648 B) per (chunk,hg)
constexpr int ATOTAL    = 12 * ASLAB_HW;              // 165888 weight elements
constexpr int TIN_HW    = PR * PC * CSL;              // 7200 hw (14400 B)
constexpr int TIN_GRAN  = TIN_HW / 8;                 // 900 granules
constexpr int ROW_HW    = 66 * CSL;                   // 2640 hw per padded image row
constexpr int PIMG_HW   = 66 * ROW_HW;                // 174240 hw per padded image

// ws layout (halfword offsets)
constexpr size_t A2_HW    = (size_t)ATOTAL;
constexpr size_t XT_OFF   = A2_HW;
constexpr size_t XT_HW    = (size_t)64 * PIMG_HW;
constexpr size_t HT_OFF   = XT_OFF + XT_HW;
constexpr size_t HTBUF_HW = (size_t)8 * PIMG_HW;      // [b4][chunk2] images
constexpr size_t FL_OFF   = HT_OFF + 2 * HTBUF_HW;    // flags (512 ints) after hT bufs
constexpr size_t WS_NEED_BYTES = (FL_OFF) * 2 + 2048;

// fused prepass block ranges
constexpr int PB_XFILL = 66 * 64;                      // 4224
constexpr int PB_WCONV = (ATOTAL + 255) / 256;         // 648
constexpr int HZ_GRAN  = (int)(2 * HTBUF_HW / 8) + 128; // hT bufs + 2KB flags
constexpr int PB_HZERO = (HZ_GRAN + 255) / 256;
constexpr int PB_TOTAL = PB_XFILL + PB_WCONV + PB_HZERO;

typedef __attribute__((ext_vector_type(8))) short bf16x8;
typedef __attribute__((ext_vector_type(4))) float f32x4;

#define GLOAD_LDS16(gsrc, ldst) \
  __builtin_amdgcn_global_load_lds((const __attribute__((address_space(1))) void*)(gsrc), \
                                   (__attribute__((address_space(3))) void*)(ldst), 16, 0, 0)

__device__ inline unsigned short f2bf(float f) {
    union { float f; unsigned u; } v; v.f = f;
    return (unsigned short)((v.u + 0x7FFFu + ((v.u >> 16) & 1u)) >> 16);
}
__device__ inline float bf2f(unsigned short h) {
    union { unsigned u; float f; } v; v.u = (unsigned)h << 16; return v.f;
}

// ---- fused prepass: xfill | wconv | hzero+flags (branch on block range) ----
__global__ void prep(const float* __restrict__ x,
                     const float* __restrict__ Wi, const float* __restrict__ Wh,
                     unsigned short* __restrict__ A2,
                     unsigned short* __restrict__ xT,
                     unsigned short* __restrict__ hT) {
    __shared__ float lds[64 * 41];
    const int bid = blockIdx.x;

    if (bid < PB_XFILL) {
        const int riT = bid % 66;
        const int bt  = bid / 66;
        unsigned short* dst = xT + (size_t)bt * PIMG_HW + (size_t)riT * ROW_HW;
        const bool interior = (riT >= 1 && riT <= 64);
        if (interior) {
            const float* src = x + (size_t)bt * 32 * HW + (riT - 1) * WW;
            const int p = threadIdx.x & 63;
            #pragma unroll
            for (int j = 0; j < 8; ++j) {
                int c = j * 4 + (threadIdx.x >> 6);
                lds[p * 41 + c] = src[c * HW + p];
            }
        }
        __syncthreads();
        for (int g = threadIdx.x; g < ROW_HW / 8; g += 256) {
            bf16x8 vv;
            #pragma unroll
            for (int k = 0; k < 8; ++k) {
                int off = g * 8 + k;
                int px = off / CSL, slot = off - px * CSL;
                float v = 0.f;
                if (interior && slot < 32 && px >= 1 && px <= 64)
                    v = lds[(px - 1) * 41 + slot];
                vv[k] = (short)f2bf(v);
            }
            *(bf16x8*)(dst + g * 8) = vv;
        }
    } else if (bid < PB_XFILL + PB_WCONV) {
        int idx = (bid - PB_XFILL) * 256 + threadIdx.x;
        if (idx >= ATOTAL) return;
        int ic  = idx & 31;
        int r1  = idx >> 5;
        int tap = r1 % 9;
        int r2  = r1 / 9;
        int m   = r2 & 15;
        int r3  = r2 >> 4;
        int gt  = r3 % 3;
        int r4  = r3 / 3;
        int hg  = r4 & 3;
        int ch  = r4 >> 2;
        int o   = gt * 64 + hg * 16 + m;
        float w = (ch == 0) ? Wi[(o * CIN + ic) * 9 + tap]
                            : Wh[(o * HID + (ch - 1) * 32 + ic) * 9 + tap];
        size_t dst = (size_t)(ch * 4 + hg) * ASLAB_HW
                   + ((size_t)(gt * 36 + tap * 4 + (ic >> 3)) * 16 + m) * 8 + (ic & 7);
        A2[dst] = f2bf(w);
    } else {
        int i = (bid - PB_XFILL - PB_WCONV) * 256 + threadIdx.x;
        if (i < HZ_GRAN) ((f32x4*)hT)[i] = f32x4{0.f, 0.f, 0.f, 0.f};
    }
}

// ================= persistent all-steps kernel (coop residency + halo flags) ==========
// grid (32 tiles, 4 hg, 4 b) = 512 blocks = 2/CU; 256 thr.
__global__ __launch_bounds__(256, 2) void convgru_pers(
    const unsigned short* __restrict__ xT,
    const unsigned short* __restrict__ A2,
    unsigned short* __restrict__ hT0,
    unsigned short* __restrict__ hT1,
    int* __restrict__ flags,
    float* __restrict__ out)
{
    __shared__ __align__(16) unsigned short tXa[TIN_HW];
    __shared__ __align__(16) unsigned short tXb[TIN_HW];
    __shared__ __align__(16) unsigned short tL[TIN_HW];
    __shared__ __align__(16) unsigned short tH[TIN_HW];

    const int tid  = threadIdx.x;
    const int lane = tid & 63, wave = tid >> 6;
    const int px   = lane & 15, kl = lane >> 4;
    const int ty = blockIdx.x >> 2, tx = blockIdx.x & 3;
    const int hg = blockIdx.y, b = blockIdx.z;
    const int gy0 = ty * TR, gx0 = tx * TC;
    const int rowbase = gy0 * 66 + gx0;

    // my flag + (for lanes 0..35) one neighborhood flag to poll
    const int myflag = (b * 4 + hg) * 32 + (int)blockIdx.x;
    int nbrflag = myflag;
    if (tid < 36) {
        int s = tid >> 2, hgn = tid & 3;
        int nty = ty + s / 3 - 1, ntx = tx + s % 3 - 1;
        nty = nty < 0 ? 0 : (nty > 7 ? 7 : nty);
        ntx = ntx < 0 ? 0 : (ntx > 3 ? 3 : ntx);
        nbrflag = (b * 4 + hgn) * 32 + nty * 4 + ntx;
    }

    const unsigned short* A0p = A2 + (size_t)(0 * 4 + hg) * ASLAB_HW + lane * 8;
    const unsigned short* A1p = A2 + (size_t)(1 * 4 + hg) * ASLAB_HW + lane * 8;
    const unsigned short* A2p = A2 + (size_t)(2 * 4 + hg) * ASLAB_HW + lane * 8;

    f32x4 accR[2], accZ[2], accNX[2], accNH[2];
    bf16x8 a[27];

    auto stage_tin = [&](const unsigned short* src, unsigned short* dst) {
        #pragma unroll
        for (int j = 0; j < 4; ++j) {
            int G = tid + j * 256;
            if (G < TIN_GRAN) {
                int r = G / 90, w = G - 90 * r;
                GLOAD_LDS16(src + (size_t)(rowbase + r * 66) * CSL + w * 8, dst + G * 8);
            }
        }
    };
    const int rb = (wave * 2 * PC + px) * CSL + kl * 8;

    auto compute = [&](const unsigned short* tb, bool isX, const unsigned short* nextA) {
        bf16x8 P[4][3];
        #pragma unroll
        for (int r = 0; r < 4; ++r)
            #pragma unroll
            for (int s = 0; s < 3; ++s)
                P[r][s] = *(const bf16x8*)(tb + rb + (r * PC + s) * CSL);
        #pragma unroll
        for (int dy = 0; dy < 3; ++dy) {
            #pragma unroll
            for (int dx = 0; dx < 3; ++dx) {
                const int tap = dy * 3 + dx;
                bf16x8 b0 = P[dy][dx], b1 = P[dy + 1][dx];
                bf16x8 ar = a[tap], az = a[9 + tap], an = a[18 + tap];
                if (nextA) {
                    a[tap]      = *(const bf16x8*)(nextA + (size_t)(0 * 36 + tap * 4) * 128);
                    a[9 + tap]  = *(const bf16x8*)(nextA + (size_t)(1 * 36 + tap * 4) * 128);
                    a[18 + tap] = *(const bf16x8*)(nextA + (size_t)(2 * 36 + tap * 4) * 128);
                }
                accR[0] = __builtin_amdgcn_mfma_f32_16x16x32_bf16(ar, b0, accR[0], 0, 0, 0);
                accR[1] = __builtin_amdgcn_mfma_f32_16x16x32_bf16(ar, b1, accR[1], 0, 0, 0);
                accZ[0] = __builtin_amdgcn_mfma_f32_16x16x32_bf16(az, b0, accZ[0], 0, 0, 0);
                accZ[1] = __builtin_amdgcn_mfma_f32_16x16x32_bf16(az, b1, accZ[1], 0, 0, 0);
                if (isX) {
                    accNX[0] = __builtin_amdgcn_mfma_f32_16x16x32_bf16(an, b0, accNX[0], 0, 0, 0);
                    accNX[1] = __builtin_amdgcn_mfma_f32_16x16x32_bf16(an, b1, accNX[1], 0, 0, 0);
                } else {
                    accNH[0] = __builtin_amdgcn_mfma_f32_16x16x32_bf16(an, b0, accNH[0], 0, 0, 0);
                    accNH[1] = __builtin_amdgcn_mfma_f32_16x16x32_bf16(an, b1, accNH[1], 0, 0, 0);
                }
            }
        }
    };

    auto epilogue = [&](int t, unsigned short* hTwr) {
        float* outp = out + ((size_t)(b * T_ + t)) * HID * HW;
        const int c0   = hg * 16 + kl * 4;
        const int slot = c0 & 31;
        const unsigned short* hbuf = (hg < 2) ? tL : tH;
        #pragma unroll
        for (int g = 0; g < 2; ++g) {
            int gy = gy0 + wave * 2 + g;
            int gx = gx0 + px;
            float hvf[4] = {0.f, 0.f, 0.f, 0.f};
            if (t > 0) {
                const unsigned short* hp =
                    hbuf + ((wave * 2 + g + 1) * PC + (px + 1)) * CSL + slot;
                #pragma unroll
                for (int q = 0; q < 4; ++q) hvf[q] = bf2f(hp[q]);
            }
            unsigned short hvals[4];
            #pragma unroll
            for (int q = 0; q < 4; ++q) {
                int c = c0 + q;
                float sr = __builtin_amdgcn_rcpf(1.f + __expf(-accR[g][q]));
                float sz = __builtin_amdgcn_rcpf(1.f + __expf(-accZ[g][q]));
                float ag = accNX[g][q] + sr * accNH[g][q];
                float nn = 2.f * __builtin_amdgcn_rcpf(1.f + __expf(-2.f * ag)) - 1.f;
                float hn = nn + sz * (hvf[q] - nn);
                outp[(size_t)c * HW + gy * WW + gx] = hn;
                hvals[q] = f2bf(hn);
            }
            unsigned short* hd = hTwr + (size_t)(b * 2 + (c0 >> 5)) * PIMG_HW
                               + (size_t)((gy + 1) * 66 + (gx + 1)) * CSL + slot;
            *(uint2*)hd = *(const uint2*)hvals;
        }
    };

    // preload A(0)
    #pragma unroll
    for (int i = 0; i < 27; ++i)
        a[i] = *(const bf16x8*)(A0p + (size_t)((i / 9) * 36 + (i % 9) * 4) * 128);

    // ---- t = 0 (x-chunk only) ----
    stage_tin(xT + (size_t)(b * T_) * PIMG_HW, tXa);
    __syncthreads();
    #pragma unroll
    for (int i = 0; i < 2; ++i) {
        accR[i] = f32x4{0.f,0.f,0.f,0.f}; accZ[i] = f32x4{0.f,0.f,0.f,0.f};
        accNX[i] = f32x4{0.f,0.f,0.f,0.f}; accNH[i] = f32x4{0.f,0.f,0.f,0.f};
    }
    compute(tXa, true, nullptr);                 // keeps A(0) in regs
    stage_tin(xT + (size_t)(b * T_ + 1) * PIMG_HW, tXb);   // prefetch x(1)
    epilogue(0, hT1);
    __threadfence();
    __syncthreads();
    if (tid == 0)
        __hip_atomic_store(&flags[myflag], 1, __ATOMIC_RELAXED, __HIP_MEMORY_SCOPE_AGENT);

    // ---- t = 1..15 ----
    for (int t = 1; t < T_; ++t) {
        if (tid < 36) {
            while (__hip_atomic_load(&flags[nbrflag], __ATOMIC_RELAXED,
                                     __HIP_MEMORY_SCOPE_AGENT) < t)
                __builtin_amdgcn_s_sleep(2);
        }
        __syncthreads();
        __threadfence();                         // acquire: invalidate stale cache

        const unsigned short* hTrd = (t & 1) ? hT1 : hT0;
        unsigned short*       hTwr = (t & 1) ? hT0 : hT1;
        stage_tin(hTrd + (size_t)(b * 2 + 0) * PIMG_HW, tL);
        stage_tin(hTrd + (size_t)(b * 2 + 1) * PIMG_HW, tH);
        __syncthreads();                         // drains h DMA + x prefetch

        #pragma unroll
        for (int i = 0; i < 2; ++i) {
            accR[i] = f32x4{0.f,0.f,0.f,0.f}; accZ[i] = f32x4{0.f,0.f,0.f,0.f};
            accNX[i] = f32x4{0.f,0.f,0.f,0.f}; accNH[i] = f32x4{0.f,0.f,0.f,0.f};
        }
        compute((t & 1) ? tXb : tXa, true, A1p);
        if (t + 1 < T_)
            stage_tin(xT + (size_t)(b * T_ + t + 1) * PIMG_HW, (t & 1) ? tXa : tXb);
        compute(tL, false, A2p);
        compute(tH, false, A0p);                 // reload A(0) for next step's x
        epilogue(t, hTwr);
        __threadfence();
        __syncthreads();
        if (tid == 0)
            __hip_atomic_store(&flags[myflag], t + 1, __ATOMIC_RELAXED, __HIP_MEMORY_SCOPE_AGENT);
    }
}

// ================= r11 per-step kernel (fallback if coop launch fails) =================
__global__ __launch_bounds__(256, 2) void convgru_mfma(
    const unsigned short* __restrict__ xT,
    const unsigned short* __restrict__ A2,
    const unsigned short* __restrict__ hTrd,
    unsigned short* __restrict__ hTwr,
    float* __restrict__ out, int t)
{
    __shared__ __align__(16) unsigned short t0s[TIN_HW];
    __shared__ __align__(16) unsigned short t1s[TIN_HW];
    __shared__ __align__(16) unsigned short t2s[TIN_HW];

    const int tid  = threadIdx.x;
    const int lane = tid & 63, wave = tid >> 6;
    const int px   = lane & 15, kl = lane >> 4;
    const int ty = blockIdx.x >> 2, tx = blockIdx.x & 3;
    const int hg = blockIdx.y, b = blockIdx.z;
    const int gy0 = ty * TR, gx0 = tx * TC;

    const unsigned short* xs = xT + (size_t)(b * T_ + t) * PIMG_HW;
    const int rowbase = gy0 * 66 + gx0;

    f32x4 accR[2] = {}, accZ[2] = {}, accNX[2] = {}, accNH[2] = {};
    bf16x8 a[27];

    auto stage_tin = [&](const unsigned short* src, unsigned short* dst) {
        #pragma unroll
        for (int j = 0; j < 4; ++j) {
            int G = tid + j * 256;
            if (G < TIN_GRAN) {
                int r = G / 90, w = G - 90 * r;
                GLOAD_LDS16(src + (size_t)(rowbase + r * 66) * CSL + w * 8, dst + G * 8);
            }
        }
    };
    auto regA = [&](int ch) {
        const unsigned short* s = A2 + (size_t)(ch * 4 + hg) * ASLAB_HW + lane * 8;
        #pragma unroll
        for (int i = 0; i < 27; ++i)
            a[i] = *(const bf16x8*)(s + (size_t)((i / 9) * 36 + (i % 9) * 4) * 128);
    };
    const int rb = (wave * 2 * PC + px) * CSL + kl * 8;

    auto compute = [&](const unsigned short* tb, bool isX, const unsigned short* nextA) {
        bf16x8 P[4][3];
        #pragma unroll
        for (int r = 0; r < 4; ++r)
            #pragma unroll
            for (int s = 0; s < 3; ++s)
                P[r][s] = *(const bf16x8*)(tb + rb + (r * PC + s) * CSL);
        #pragma unroll
        for (int dy = 0; dy < 3; ++dy) {
            #pragma unroll
            for (int dx = 0; dx < 3; ++dx) {
                const int tap = dy * 3 + dx;
                bf16x8 b0 = P[dy][dx], b1 = P[dy + 1][dx];
                bf16x8 ar = a[tap], az = a[9 + tap], an = a[18 + tap];
                if (nextA) {
                    a[tap]      = *(const bf16x8*)(nextA + (size_t)(0 * 36 + tap * 4) * 128);
                    a[9 + tap]  = *(const bf16x8*)(nextA + (size_t)(1 * 36 + tap * 4) * 128);
                    a[18 + tap] = *(const bf16x8*)(nextA + (size_t)(2 * 36 + tap * 4) * 128);
                }
                accR[0] = __builtin_amdgcn_mfma_f32_16x16x32_bf16(ar, b0, accR[0], 0, 0, 0);
                accR[1] = __builtin_amdgcn_mfma_f32_16x16x32_bf16(ar, b1, accR[1], 0, 0, 0);
                accZ[0] = __builtin_amdgcn_mfma_f32_16x16x32_bf16(az, b0, accZ[0], 0, 0, 0);
                accZ[1] = __builtin_amdgcn_mfma_f32_16x16x32_bf16(az, b1, accZ[1], 0, 0, 0);
                if (isX) {
                    accNX[0] = __builtin_amdgcn_mfma_f32_16x16x32_bf16(an, b0, accNX[0], 0, 0, 0);
                    accNX[1] = __builtin_amdgcn_mfma_f32_16x16x32_bf16(an, b1, accNX[1], 0, 0, 0);
                } else {
                    accNH[0] = __builtin_amdgcn_mfma_f32_16x16x32_bf16(an, b0, accNH[0], 0, 0, 0);
                    accNH[1] = __builtin_amdgcn_mfma_f32_16x16x32_bf16(an, b1, accNH[1], 0, 0, 0);
                }
            }
        }
    };

    stage_tin(xs, t0s);
    if (t > 0) {
        stage_tin(hTrd + (size_t)(b * 2 + 0) * PIMG_HW, t1s);
        stage_tin(hTrd + (size_t)(b * 2 + 1) * PIMG_HW, t2s);
    }
    regA(0);
    __syncthreads();

    const unsigned short* A1p = (t > 0) ? A2 + (size_t)(1 * 4 + hg) * ASLAB_HW + lane * 8 : nullptr;
    const unsigned short* A2p = (t > 0) ? A2 + (size_t)(2 * 4 + hg) * ASLAB_HW + lane * 8 : nullptr;

    compute(t0s, true, A1p);
    if (t > 0) {
        compute(t1s, false, A2p);
        compute(t2s, false, nullptr);
    }

    float* outp = out + ((size_t)(b * T_ + t)) * HID * HW;
    const int c0   = hg * 16 + kl * 4;
    const int slot = c0 & 31;
    const unsigned short* hbuf = (hg < 2) ? t1s : t2s;
    #pragma unroll
    for (int g = 0; g < 2; ++g) {
        int gy = gy0 + wave * 2 + g;
        int gx = gx0 + px;
        float hvf[4] = {0.f, 0.f, 0.f, 0.f};
        if (t > 0) {
            const unsigned short* hp =
                hbuf + ((wave * 2 + g + 1) * PC + (px + 1)) * CSL + slot;
            #pragma unroll
            for (int q = 0; q < 4; ++q) hvf[q] = bf2f(hp[q]);
        }
        unsigned short hvals[4];
        #pragma unroll
        for (int q = 0; q < 4; ++q) {
            int c = c0 + q;
            float sr = __builtin_amdgcn_rcpf(1.f + __expf(-accR[g][q]));
            float sz = __builtin_amdgcn_rcpf(1.f + __expf(-accZ[g][q]));
            float ag = accNX[g][q] + sr * accNH[g][q];
            float nn = 2.f * __builtin_amdgcn_rcpf(1.f + __expf(-2.f * ag)) - 1.f;
            float hn = nn + sz * (hvf[q] - nn);
            outp[(size_t)c * HW + gy * WW + gx] = hn;
            hvals[q] = f2bf(hn);
        }
        unsigned short* hd = hTwr + (size_t)(b * 2 + (c0 >> 5)) * PIMG_HW
                           + (size_t)((gy + 1) * 66 + (gx + 1)) * CSL + slot;
        *(uint2*)hd = *(const uint2*)hvals;
    }
}

// ================= round-4 fallback (tiny ws) =================
constexpr int F_AROWB = 640;
constexpr int R4_ASLAB = 48 * 9 * KCH;
constexpr int R4_AVEC  = R4_ASLAB / 8;
constexpr int R4_ATOT  = 12 * R4_ASLAB;
__global__ void wconv_r4(const float* __restrict__ Wi, const float* __restrict__ Wh,
                         unsigned short* __restrict__ A2) {
    int idx = blockIdx.x * 256 + threadIdx.x;
    if (idx >= R4_ATOT) return;
    int ic = idx & 31; int r1 = idx >> 5;
    int tap = r1 % 9; int r2 = r1 / 9;
    int m = r2 & 15; int r3 = r2 >> 4;
    int gt = r3 % 3; int r4 = r3 / 3;
    int hg = r4 & 3; int ch = r4 >> 2;
    int o = gt * 64 + hg * 16 + m;
    float w = (ch == 0) ? Wi[(o * CIN + ic) * 9 + tap]
                        : Wh[(o * HID + (ch - 1) * 32 + ic) * 9 + tap];
    A2[idx] = f2bf(w);
}
__global__ __launch_bounds__(256, 2) void convgru_r4(
    const float* __restrict__ x, const unsigned short* __restrict__ A2,
    const float* hall, float* out, int t)
{
    __shared__ __align__(16) unsigned short tin[PR * PC * 40];
    __shared__ __align__(16) unsigned short Alr[48 * (F_AROWB / 2)];
    const int tid = threadIdx.x;
    const int lane = tid & 63, wave = tid >> 6;
    const int px = lane & 15, kl = lane >> 4;
    const int ty = blockIdx.x >> 2, tx = blockIdx.x & 3;
    const int hg = blockIdx.y, b = blockIdx.z;
    const int gy0 = ty * TR, gx0 = tx * TC;
    const int nch = (t > 0) ? 3 : 1;
    const float* hb = (t > 0) ? (hall + ((size_t)(b * T_ + t - 1)) * HID * HW) : nullptr;
    const float* xb = x + ((size_t)(b * T_ + t)) * CIN * HW;
    f32x4 accR[2] = {}, accZ[2] = {}, accNX[2] = {}, accNH[2] = {};
    float ireg[23]; bf16x8 areg[7];
    auto load_in = [&](int ch) {
        const float* src = (ch == 0) ? xb : (hb + (size_t)(ch - 1) * KCH * HW);
        #pragma unroll
        for (int j = 0; j < 23; ++j) {
            int e = tid + j * 256; float v = 0.f;
            if (e < PR * PC * KCH) {
                int ic = e / (PR * PC); int rem = e - ic * (PR * PC);
                int r = rem / PC, c = rem - r * PC;
                int gy = gy0 + r - 1, gx = gx0 + c - 1;
                if ((unsigned)gy < (unsigned)HH && (unsigned)gx < (unsigned)WW)
                    v = src[ic * HW + gy * WW + gx];
            }
            ireg[j] = v;
        }
    };
    auto load_Ar = [&](int ch) {
        const unsigned short* s = A2 + (size_t)(ch * 4 + hg) * R4_ASLAB;
        #pragma unroll
        for (int j = 0; j < 7; ++j) { int v = tid + j * 256; if (v < R4_AVEC) areg[j] = *(const bf16x8*)(s + v * 8); }
    };
    auto write_in = [&]() {
        #pragma unroll
        for (int j = 0; j < 23; ++j) {
            int e = tid + j * 256;
            if (e < PR * PC * KCH) {
                int ic = e / (PR * PC); int rem = e - ic * (PR * PC);
                int r = rem / PC, c = rem - r * PC;
                tin[(r * PC + c) * 40 + ic] = f2bf(ireg[j]);
            }
        }
    };
    auto write_Ar = [&]() {
        #pragma unroll
        for (int j = 0; j < 7; ++j) {
            int v = tid + j * 256;
            if (v < R4_AVEC) {
                int row = v / 36; int kb = (v - row * 36) * 16;
                char* dst = (char*)Alr + row * F_AROWB + (kb ^ ((row & 7) << 4));
                *(bf16x8*)dst = areg[j];
            }
        }
    };
    const int rb0 = ((wave * 2 + 0) * PC + px) * 40 + kl * 8;
    const int rb1 = rb0 + PC * 40;
    const int swA = (px & 7) << 4;
    auto compute = [&](bool isX) {
        #pragma unroll
        for (int tap = 0; tap < 9; ++tap) {
            const int dy = tap / 3, dx = tap - 3 * dy;
            const int toff = (dy * PC + dx) * 40;
            bf16x8 b0 = *(const bf16x8*)(tin + rb0 + toff);
            bf16x8 b1 = *(const bf16x8*)(tin + rb1 + toff);
            const char* ab = (const char*)Alr + px * F_AROWB + ((tap * 64 + kl * 16) ^ swA);
            bf16x8 ar = *(const bf16x8*)(ab);
            bf16x8 az = *(const bf16x8*)(ab + 16 * F_AROWB);
            bf16x8 an = *(const bf16x8*)(ab + 32 * F_AROWB);
            accR[0] = __builtin_amdgcn_mfma_f32_16x16x32_bf16(ar, b0, accR[0], 0, 0, 0);
            accR[1] = __builtin_amdgcn_mfma_f32_16x16x32_bf16(ar, b1, accR[1], 0, 0, 0);
            accZ[0] = __builtin_amdgcn_mfma_f32_16x16x32_bf16(az, b0, accZ[0], 0, 0, 0);
            accZ[1] = __builtin_amdgcn_mfma_f32_16x16x32_bf16(az, b1, accZ[1], 0, 0, 0);
            if (isX) {
                accNX[0] = __builtin_amdgcn_mfma_f32_16x16x32_bf16(an, b0, accNX[0], 0, 0, 0);
                accNX[1] = __builtin_amdgcn_mfma_f32_16x16x32_bf16(an, b1, accNX[1], 0, 0, 0);
            } else {
                accNH[0] = __builtin_amdgcn_mfma_f32_16x16x32_bf16(an, b0, accNH[0], 0, 0, 0);
                accNH[1] = __builtin_amdgcn_mfma_f32_16x16x32_bf16(an, b1, accNH[1], 0, 0, 0);
            }
        }
    };
    load_in(0); load_Ar(0); write_in(); write_Ar();
    __syncthreads();
    for (int ch = 0; ch < nch; ++ch) {
        if (ch + 1 < nch) { load_in(ch + 1); load_Ar(ch + 1); }
        compute(ch == 0);
        __syncthreads();
        if (ch + 1 < nch) { write_in(); write_Ar(); __syncthreads(); }
    }
    float* outp = out + ((size_t)(b * T_ + t)) * HID * HW;
    #pragma unroll
    for (int g = 0; g < 2; ++g) {
        int gy = gy0 + wave * 2 + g; int gx = gx0 + px;
        #pragma unroll
        for (int q = 0; q < 4; ++q) {
            int c = hg * 16 + kl * 4 + q;
            float sr = 1.f / (1.f + expf(-accR[g][q]));
            float sz = 1.f / (1.f + expf(-accZ[g][q]));
            float nn = tanhf(accNX[g][q] + sr * accNH[g][q]);
            float hv = hb ? hb[(size_t)c * HW + gy * WW + gx] : 0.f;
            outp[(size_t)c * HW + gy * WW + gx] = (1.f - sz) * nn + sz * hv;
        }
    }
}

extern "C" void kernel_launch(void* const* d_in, const int* in_sizes, int n_in,
                              void* d_out, int out_size, void* d_ws, size_t ws_size,
                              hipStream_t stream) {
    const float* x  = (const float*)d_in[0];
    const float* Wi = (const float*)d_in[1];
    const float* Wh = (const float*)d_in[2];
    float* out = (float*)d_out;

    if (ws_size >= WS_NEED_BYTES) {
        unsigned short* A2  = (unsigned short*)d_ws;
        unsigned short* xT  = A2 + XT_OFF;
        unsigned short* hT0 = A2 + HT_OFF;
        unsigned short* hT1 = hT0 + HTBUF_HW;
        int* flags = (int*)(A2 + FL_OFF);

        prep<<<PB_TOTAL, 256, 0, stream>>>(x, Wi, Wh, A2, xT, hT0);

        const unsigned short* xTc = xT;
        const unsigned short* A2c = A2;
        void* args[] = { (void*)&xTc, (void*)&A2c, (void*)&hT0, (void*)&hT1,
                         (void*)&flags, (void*)&out };
        hipError_t e = hipLaunchCooperativeKernel((void*)convgru_pers, dim3(32, 4, 4),
                                                  dim3(256, 1, 1), args, 0, stream);
        if (e != hipSuccess) {
            for (int t = 0; t < T_; ++t) {
                unsigned short* rd = (t & 1) ? hT1 : hT0;
                unsigned short* wr = (t & 1) ? hT0 : hT1;
                convgru_mfma<<<dim3(32, 4, 4), 256, 0, stream>>>(xT, A2, rd, wr, out, t);
            }
        }
    } else {
        unsigned short* A2 = (unsigned short*)d_ws;
        wconv_r4<<<(R4_ATOT + 255) / 256, 256, 0, stream>>>(Wi, Wh, A2);
        for (int t = 0; t < T_; ++t)
            convgru_r4<<<dim3(32, 4, 4), 256, 0, stream>>>(x, A2, out, out, t);
    }
}

// Round 13
// 837.560 us; speedup vs baseline: 2.7166x; 2.7166x over previous
//
#include <hip/hip_runtime.h>
#include <math.h>

// Problem dims
constexpr int B_  = 4;
constexpr int T_  = 16;
constexpr int CIN = 32;
constexpr int HID = 64;
constexpr int HH  = 64;
constexpr int WW  = 64;
constexpr int HW  = HH * WW; // 4096

// ---------------- MFMA path config ----------------
constexpr int TR = 8,  TC = 16;         // output pixel tile: 8 rows x 16 cols
constexpr int PR = TR + 2, PC = TC + 2; // 10 x 18 (halo)
constexpr int CSL = 40;                 // channel slots per pixel (80B)
constexpr int KCH = 32;                 // channels per K-chunk
constexpr int ASLAB_HW  = 3 * 36 * 16 * 8;            // 13824 hw (27648 B) per (chunk,hg)
constexpr int ATOTAL    = 12 * ASLAB_HW;              // 165888 weight elements
constexpr int TIN_HW    = PR * PC * CSL;              // 7200 hw (14400 B)
constexpr int TIN_GRAN  = TIN_HW / 8;                 // 900 16B granules
constexpr int TIN_G8    = TIN_HW / 4;                 // 1800 8B granules
constexpr int ROW_G8    = PC * CSL / 4;               // 180 8B granules per halo row
constexpr int ROW_HW    = 66 * CSL;                   // 2640 hw per padded image row
constexpr int PIMG_HW   = 66 * ROW_HW;                // 174240 hw per padded image

// ws layout (halfword offsets)
constexpr size_t A2_HW    = (size_t)ATOTAL;
constexpr size_t XT_OFF   = A2_HW;
constexpr size_t XT_HW    = (size_t)64 * PIMG_HW;
constexpr size_t HT_OFF   = XT_OFF + XT_HW;
constexpr size_t HTBUF_HW = (size_t)8 * PIMG_HW;      // [b4][chunk2] images
constexpr size_t FL_OFF   = HT_OFF + 2 * HTBUF_HW;    // flags (512 ints)
constexpr size_t WS_NEED_BYTES = (FL_OFF) * 2 + 2048;

// fused prepass block ranges
constexpr int PB_XFILL = 66 * 64;                      // 4224
constexpr int PB_WCONV = (ATOTAL + 255) / 256;         // 648
constexpr int HZ_GRAN  = (int)(2 * HTBUF_HW / 8) + 128; // hT bufs + 2KB flags
constexpr int PB_HZERO = (HZ_GRAN + 255) / 256;
constexpr int PB_TOTAL = PB_XFILL + PB_WCONV + PB_HZERO;

typedef __attribute__((ext_vector_type(8))) short bf16x8;
typedef __attribute__((ext_vector_type(4))) float f32x4;

#define GLOAD_LDS16(gsrc, ldst) \
  __builtin_amdgcn_global_load_lds((const __attribute__((address_space(1))) void*)(gsrc), \
                                   (__attribute__((address_space(3))) void*)(ldst), 16, 0, 0)

__device__ inline unsigned short f2bf(float f) {
    union { float f; unsigned u; } v; v.f = f;
    return (unsigned short)((v.u + 0x7FFFu + ((v.u >> 16) & 1u)) >> 16);
}
__device__ inline float bf2f(unsigned short h) {
    union { unsigned u; float f; } v; v.u = (unsigned)h << 16; return v.f;
}

// ---- fused prepass: xfill | wconv | hzero+flags ----
__global__ void prep(const float* __restrict__ x,
                     const float* __restrict__ Wi, const float* __restrict__ Wh,
                     unsigned short* __restrict__ A2,
                     unsigned short* __restrict__ xT,
                     unsigned short* __restrict__ hT) {
    __shared__ float lds[64 * 41];
    const int bid = blockIdx.x;

    if (bid < PB_XFILL) {
        const int riT = bid % 66;
        const int bt  = bid / 66;
        unsigned short* dst = xT + (size_t)bt * PIMG_HW + (size_t)riT * ROW_HW;
        const bool interior = (riT >= 1 && riT <= 64);
        if (interior) {
            const float* src = x + (size_t)bt * 32 * HW + (riT - 1) * WW;
            const int p = threadIdx.x & 63;
            #pragma unroll
            for (int j = 0; j < 8; ++j) {
                int c = j * 4 + (threadIdx.x >> 6);
                lds[p * 41 + c] = src[c * HW + p];
            }
        }
        __syncthreads();
        for (int g = threadIdx.x; g < ROW_HW / 8; g += 256) {
            bf16x8 vv;
            #pragma unroll
            for (int k = 0; k < 8; ++k) {
                int off = g * 8 + k;
                int px = off / CSL, slot = off - px * CSL;
                float v = 0.f;
                if (interior && slot < 32 && px >= 1 && px <= 64)
                    v = lds[(px - 1) * 41 + slot];
                vv[k] = (short)f2bf(v);
            }
            *(bf16x8*)(dst + g * 8) = vv;
        }
    } else if (bid < PB_XFILL + PB_WCONV) {
        int idx = (bid - PB_XFILL) * 256 + threadIdx.x;
        if (idx >= ATOTAL) return;
        int ic  = idx & 31;
        int r1  = idx >> 5;
        int tap = r1 % 9;
        int r2  = r1 / 9;
        int m   = r2 & 15;
        int r3  = r2 >> 4;
        int gt  = r3 % 3;
        int r4  = r3 / 3;
        int hg  = r4 & 3;
        int ch  = r4 >> 2;
        int o   = gt * 64 + hg * 16 + m;
        float w = (ch == 0) ? Wi[(o * CIN + ic) * 9 + tap]
                            : Wh[(o * HID + (ch - 1) * 32 + ic) * 9 + tap];
        size_t dst = (size_t)(ch * 4 + hg) * ASLAB_HW
                   + ((size_t)(gt * 36 + tap * 4 + (ic >> 3)) * 16 + m) * 8 + (ic & 7);
        A2[dst] = f2bf(w);
    } else {
        int i = (bid - PB_XFILL - PB_WCONV) * 256 + threadIdx.x;
        if (i < HZ_GRAN) ((f32x4*)hT)[i] = f32x4{0.f, 0.f, 0.f, 0.f};
    }
}

// ========== persistent all-steps kernel: NO fences; h + flags via agent atomics ==========
// grid (32 tiles, 4 hg, 4 b) = 512 blocks = 2/CU; 256 thr.
__global__ __launch_bounds__(256, 2) void convgru_pers(
    const unsigned short* __restrict__ xT,
    const unsigned short* __restrict__ A2,
    unsigned short* __restrict__ hT0,
    unsigned short* __restrict__ hT1,
    int* __restrict__ flags,
    float* __restrict__ out)
{
    __shared__ __align__(16) unsigned short tXa[TIN_HW];
    __shared__ __align__(16) unsigned short tXb[TIN_HW];
    __shared__ __align__(16) unsigned short tL[TIN_HW];
    __shared__ __align__(16) unsigned short tH[TIN_HW];

    const int tid  = threadIdx.x;
    const int lane = tid & 63, wave = tid >> 6;
    const int px   = lane & 15, kl = lane >> 4;
    const int ty = blockIdx.x >> 2, tx = blockIdx.x & 3;
    const int hg = blockIdx.y, b = blockIdx.z;
    const int gy0 = ty * TR, gx0 = tx * TC;
    const int rowbase = gy0 * 66 + gx0;

    const int myflag = (b * 4 + hg) * 32 + (int)blockIdx.x;
    int nbrflag = myflag;
    if (tid < 36) {
        int s = tid >> 2, hgn = tid & 3;
        int nty = ty + s / 3 - 1, ntx = tx + s % 3 - 1;
        nty = nty < 0 ? 0 : (nty > 7 ? 7 : nty);
        ntx = ntx < 0 ? 0 : (ntx > 3 ? 3 : ntx);
        nbrflag = (b * 4 + hgn) * 32 + nty * 4 + ntx;
    }

    const unsigned short* A0p = A2 + (size_t)(0 * 4 + hg) * ASLAB_HW + lane * 8;
    const unsigned short* A1p = A2 + (size_t)(1 * 4 + hg) * ASLAB_HW + lane * 8;
    const unsigned short* A2p = A2 + (size_t)(2 * 4 + hg) * ASLAB_HW + lane * 8;

    f32x4 accR[2], accZ[2], accNX[2], accNH[2];
    bf16x8 a[27];

    auto stage_tin = [&](const unsigned short* src, unsigned short* dst) {
        #pragma unroll
        for (int j = 0; j < 4; ++j) {
            int G = tid + j * 256;
            if (G < TIN_GRAN) {
                int r = G / 90, w = G - 90 * r;
                GLOAD_LDS16(src + (size_t)(rowbase + r * 66) * CSL + w * 8, dst + G * 8);
            }
        }
    };
    // h staging: agent-scope relaxed 8B atomic loads (bypass stale L2) -> regs
    auto load_h = [&](const unsigned short* src, unsigned long long* regs) {
        #pragma unroll
        for (int j = 0; j < 8; ++j) {
            int G = tid + j * 256;
            if (G < TIN_G8) {
                int r = G / ROW_G8, w = G - ROW_G8 * r;
                const unsigned long long* p =
                    (const unsigned long long*)(src + (size_t)(rowbase + r * 66) * CSL) + w;
                regs[j] = __hip_atomic_load(p, __ATOMIC_RELAXED, __HIP_MEMORY_SCOPE_AGENT);
            }
        }
    };
    auto write_h = [&](unsigned short* dst, const unsigned long long* regs) {
        #pragma unroll
        for (int j = 0; j < 8; ++j) {
            int G = tid + j * 256;
            if (G < TIN_G8) ((unsigned long long*)dst)[G] = regs[j];
        }
    };

    const int rb = (wave * 2 * PC + px) * CSL + kl * 8;

    auto compute = [&](const unsigned short* tb, bool isX, const unsigned short* nextA) {
        bf16x8 P[4][3];
        #pragma unroll
        for (int r = 0; r < 4; ++r)
            #pragma unroll
            for (int s = 0; s < 3; ++s)
                P[r][s] = *(const bf16x8*)(tb + rb + (r * PC + s) * CSL);
        #pragma unroll
        for (int dy = 0; dy < 3; ++dy) {
            #pragma unroll
            for (int dx = 0; dx < 3; ++dx) {
                const int tap = dy * 3 + dx;
                bf16x8 b0 = P[dy][dx], b1 = P[dy + 1][dx];
                bf16x8 ar = a[tap], az = a[9 + tap], an = a[18 + tap];
                if (nextA) {
                    a[tap]      = *(const bf16x8*)(nextA + (size_t)(0 * 36 + tap * 4) * 128);
                    a[9 + tap]  = *(const bf16x8*)(nextA + (size_t)(1 * 36 + tap * 4) * 128);
                    a[18 + tap] = *(const bf16x8*)(nextA + (size_t)(2 * 36 + tap * 4) * 128);
                }
                accR[0] = __builtin_amdgcn_mfma_f32_16x16x32_bf16(ar, b0, accR[0], 0, 0, 0);
                accR[1] = __builtin_amdgcn_mfma_f32_16x16x32_bf16(ar, b1, accR[1], 0, 0, 0);
                accZ[0] = __builtin_amdgcn_mfma_f32_16x16x32_bf16(az, b0, accZ[0], 0, 0, 0);
                accZ[1] = __builtin_amdgcn_mfma_f32_16x16x32_bf16(az, b1, accZ[1], 0, 0, 0);
                if (isX) {
                    accNX[0] = __builtin_amdgcn_mfma_f32_16x16x32_bf16(an, b0, accNX[0], 0, 0, 0);
                    accNX[1] = __builtin_amdgcn_mfma_f32_16x16x32_bf16(an, b1, accNX[1], 0, 0, 0);
                } else {
                    accNH[0] = __builtin_amdgcn_mfma_f32_16x16x32_bf16(an, b0, accNH[0], 0, 0, 0);
                    accNH[1] = __builtin_amdgcn_mfma_f32_16x16x32_bf16(an, b1, accNH[1], 0, 0, 0);
                }
            }
        }
    };

    auto epilogue = [&](int t, unsigned short* hTwr) {
        float* outp = out + ((size_t)(b * T_ + t)) * HID * HW;
        const int c0   = hg * 16 + kl * 4;
        const int slot = c0 & 31;
        const unsigned short* hbuf = (hg < 2) ? tL : tH;
        #pragma unroll
        for (int g = 0; g < 2; ++g) {
            int gy = gy0 + wave * 2 + g;
            int gx = gx0 + px;
            float hvf[4] = {0.f, 0.f, 0.f, 0.f};
            if (t > 0) {
                const unsigned short* hp =
                    hbuf + ((wave * 2 + g + 1) * PC + (px + 1)) * CSL + slot;
                #pragma unroll
                for (int q = 0; q < 4; ++q) hvf[q] = bf2f(hp[q]);
            }
            union { unsigned short s[4]; unsigned long long u; } hu;
            #pragma unroll
            for (int q = 0; q < 4; ++q) {
                int c = c0 + q;
                float sr = __builtin_amdgcn_rcpf(1.f + __expf(-accR[g][q]));
                float sz = __builtin_amdgcn_rcpf(1.f + __expf(-accZ[g][q]));
                float ag = accNX[g][q] + sr * accNH[g][q];
                float nn = 2.f * __builtin_amdgcn_rcpf(1.f + __expf(-2.f * ag)) - 1.f;
                float hn = nn + sz * (hvf[q] - nn);
                outp[(size_t)c * HW + gy * WW + gx] = hn;
                hu.s[q] = f2bf(hn);
            }
            unsigned long long* hd = (unsigned long long*)
                (hTwr + (size_t)(b * 2 + (c0 >> 5)) * PIMG_HW
                      + (size_t)((gy + 1) * 66 + (gx + 1)) * CSL + slot);
            __hip_atomic_store(hd, hu.u, __ATOMIC_RELAXED, __HIP_MEMORY_SCOPE_AGENT);
        }
    };

    // preload A(0)
    #pragma unroll
    for (int i = 0; i < 27; ++i)
        a[i] = *(const bf16x8*)(A0p + (size_t)((i / 9) * 36 + (i % 9) * 4) * 128);

    // ---- t = 0 ----
    stage_tin(xT + (size_t)(b * T_) * PIMG_HW, tXa);
    __syncthreads();
    #pragma unroll
    for (int i = 0; i < 2; ++i) {
        accR[i] = f32x4{0.f,0.f,0.f,0.f}; accZ[i] = f32x4{0.f,0.f,0.f,0.f};
        accNX[i] = f32x4{0.f,0.f,0.f,0.f}; accNH[i] = f32x4{0.f,0.f,0.f,0.f};
    }
    compute(tXa, true, nullptr);                 // A(0) stays
    stage_tin(xT + (size_t)(b * T_ + 1) * PIMG_HW, tXb);
    epilogue(0, hT1);
    asm volatile("s_waitcnt vmcnt(0)" ::: "memory");
    __syncthreads();
    if (tid == 0)
        __hip_atomic_store(&flags[myflag], 1, __ATOMIC_RELAXED, __HIP_MEMORY_SCOPE_AGENT);

    // ---- t = 1..15 ----
    for (int t = 1; t < T_; ++t) {
        if (tid < 36) {
            while (__hip_atomic_load(&flags[nbrflag], __ATOMIC_RELAXED,
                                     __HIP_MEMORY_SCOPE_AGENT) < t)
                __builtin_amdgcn_s_sleep(1);
        }
        __syncthreads();

        const unsigned short* hTrd = (t & 1) ? hT1 : hT0;
        unsigned short*       hTwr = (t & 1) ? hT0 : hT1;

        unsigned long long hrL[8], hrH[8];
        load_h(hTrd + (size_t)(b * 2 + 0) * PIMG_HW, hrL);   // in flight under x-compute

        #pragma unroll
        for (int i = 0; i < 2; ++i) {
            accR[i] = f32x4{0.f,0.f,0.f,0.f}; accZ[i] = f32x4{0.f,0.f,0.f,0.f};
            accNX[i] = f32x4{0.f,0.f,0.f,0.f}; accNH[i] = f32x4{0.f,0.f,0.f,0.f};
        }
        compute((t & 1) ? tXb : tXa, true, A1p);
        write_h(tL, hrL);
        load_h(hTrd + (size_t)(b * 2 + 1) * PIMG_HW, hrH);
        __syncthreads();                          // tL visible
        compute(tL, false, A2p);
        write_h(tH, hrH);
        if (t + 1 < T_)
            stage_tin(xT + (size_t)(b * T_ + t + 1) * PIMG_HW, (t & 1) ? tXa : tXb);
        __syncthreads();                          // tH visible (x DMA drains too)
        compute(tH, false, A0p);                  // reload A(0) for next x
        epilogue(t, hTwr);
        asm volatile("s_waitcnt vmcnt(0)" ::: "memory");
        __syncthreads();
        if (tid == 0)
            __hip_atomic_store(&flags[myflag], t + 1, __ATOMIC_RELAXED, __HIP_MEMORY_SCOPE_AGENT);
    }
}

// ================= r11 per-step kernel (fallback if coop launch fails) =================
__global__ __launch_bounds__(256, 2) void convgru_mfma(
    const unsigned short* __restrict__ xT,
    const unsigned short* __restrict__ A2,
    const unsigned short* __restrict__ hTrd,
    unsigned short* __restrict__ hTwr,
    float* __restrict__ out, int t)
{
    __shared__ __align__(16) unsigned short t0s[TIN_HW];
    __shared__ __align__(16) unsigned short t1s[TIN_HW];
    __shared__ __align__(16) unsigned short t2s[TIN_HW];

    const int tid  = threadIdx.x;
    const int lane = tid & 63, wave = tid >> 6;
    const int px   = lane & 15, kl = lane >> 4;
    const int ty = blockIdx.x >> 2, tx = blockIdx.x & 3;
    const int hg = blockIdx.y, b = blockIdx.z;
    const int gy0 = ty * TR, gx0 = tx * TC;

    const unsigned short* xs = xT + (size_t)(b * T_ + t) * PIMG_HW;
    const int rowbase = gy0 * 66 + gx0;

    f32x4 accR[2] = {}, accZ[2] = {}, accNX[2] = {}, accNH[2] = {};
    bf16x8 a[27];

    auto stage_tin = [&](const unsigned short* src, unsigned short* dst) {
        #pragma unroll
        for (int j = 0; j < 4; ++j) {
            int G = tid + j * 256;
            if (G < TIN_GRAN) {
                int r = G / 90, w = G - 90 * r;
                GLOAD_LDS16(src + (size_t)(rowbase + r * 66) * CSL + w * 8, dst + G * 8);
            }
        }
    };
    auto regA = [&](int ch) {
        const unsigned short* s = A2 + (size_t)(ch * 4 + hg) * ASLAB_HW + lane * 8;
        #pragma unroll
        for (int i = 0; i < 27; ++i)
            a[i] = *(const bf16x8*)(s + (size_t)((i / 9) * 36 + (i % 9) * 4) * 128);
    };
    const int rb = (wave * 2 * PC + px) * CSL + kl * 8;

    auto compute = [&](const unsigned short* tb, bool isX, const unsigned short* nextA) {
        bf16x8 P[4][3];
        #pragma unroll
        for (int r = 0; r < 4; ++r)
            #pragma unroll
            for (int s = 0; s < 3; ++s)
                P[r][s] = *(const bf16x8*)(tb + rb + (r * PC + s) * CSL);
        #pragma unroll
        for (int dy = 0; dy < 3; ++dy) {
            #pragma unroll
            for (int dx = 0; dx < 3; ++dx) {
                const int tap = dy * 3 + dx;
                bf16x8 b0 = P[dy][dx], b1 = P[dy + 1][dx];
                bf16x8 ar = a[tap], az = a[9 + tap], an = a[18 + tap];
                if (nextA) {
                    a[tap]      = *(const bf16x8*)(nextA + (size_t)(0 * 36 + tap * 4) * 128);
                    a[9 + tap]  = *(const bf16x8*)(nextA + (size_t)(1 * 36 + tap * 4) * 128);
                    a[18 + tap] = *(const bf16x8*)(nextA + (size_t)(2 * 36 + tap * 4) * 128);
                }
                accR[0] = __builtin_amdgcn_mfma_f32_16x16x32_bf16(ar, b0, accR[0], 0, 0, 0);
                accR[1] = __builtin_amdgcn_mfma_f32_16x16x32_bf16(ar, b1, accR[1], 0, 0, 0);
                accZ[0] = __builtin_amdgcn_mfma_f32_16x16x32_bf16(az, b0, accZ[0], 0, 0, 0);
                accZ[1] = __builtin_amdgcn_mfma_f32_16x16x32_bf16(az, b1, accZ[1], 0, 0, 0);
                if (isX) {
                    accNX[0] = __builtin_amdgcn_mfma_f32_16x16x32_bf16(an, b0, accNX[0], 0, 0, 0);
                    accNX[1] = __builtin_amdgcn_mfma_f32_16x16x32_bf16(an, b1, accNX[1], 0, 0, 0);
                } else {
                    accNH[0] = __builtin_amdgcn_mfma_f32_16x16x32_bf16(an, b0, accNH[0], 0, 0, 0);
                    accNH[1] = __builtin_amdgcn_mfma_f32_16x16x32_bf16(an, b1, accNH[1], 0, 0, 0);
                }
            }
        }
    };

    stage_tin(xs, t0s);
    if (t > 0) {
        stage_tin(hTrd + (size_t)(b * 2 + 0) * PIMG_HW, t1s);
        stage_tin(hTrd + (size_t)(b * 2 + 1) * PIMG_HW, t2s);
    }
    regA(0);
    __syncthreads();

    const unsigned short* A1p = (t > 0) ? A2 + (size_t)(1 * 4 + hg) * ASLAB_HW + lane * 8 : nullptr;
    const unsigned short* A2p = (t > 0) ? A2 + (size_t)(2 * 4 + hg) * ASLAB_HW + lane * 8 : nullptr;

    compute(t0s, true, A1p);
    if (t > 0) {
        compute(t1s, false, A2p);
        compute(t2s, false, nullptr);
    }

    float* outp = out + ((size_t)(b * T_ + t)) * HID * HW;
    const int c0   = hg * 16 + kl * 4;
    const int slot = c0 & 31;
    const unsigned short* hbuf = (hg < 2) ? t1s : t2s;
    #pragma unroll
    for (int g = 0; g < 2; ++g) {
        int gy = gy0 + wave * 2 + g;
        int gx = gx0 + px;
        float hvf[4] = {0.f, 0.f, 0.f, 0.f};
        if (t > 0) {
            const unsigned short* hp =
                hbuf + ((wave * 2 + g + 1) * PC + (px + 1)) * CSL + slot;
            #pragma unroll
            for (int q = 0; q < 4; ++q) hvf[q] = bf2f(hp[q]);
        }
        unsigned short hvals[4];
        #pragma unroll
        for (int q = 0; q < 4; ++q) {
            int c = c0 + q;
            float sr = __builtin_amdgcn_rcpf(1.f + __expf(-accR[g][q]));
            float sz = __builtin_amdgcn_rcpf(1.f + __expf(-accZ[g][q]));
            float ag = accNX[g][q] + sr * accNH[g][q];
            float nn = 2.f * __builtin_amdgcn_rcpf(1.f + __expf(-2.f * ag)) - 1.f;
            float hn = nn + sz * (hvf[q] - nn);
            outp[(size_t)c * HW + gy * WW + gx] = hn;
            hvals[q] = f2bf(hn);
        }
        unsigned short* hd = hTwr + (size_t)(b * 2 + (c0 >> 5)) * PIMG_HW
                           + (size_t)((gy + 1) * 66 + (gx + 1)) * CSL + slot;
        *(uint2*)hd = *(const uint2*)hvals;
    }
}

// ================= round-4 fallback (tiny ws) =================
constexpr int F_AROWB = 640;
constexpr int R4_ASLAB = 48 * 9 * KCH;
constexpr int R4_AVEC  = R4_ASLAB / 8;
constexpr int R4_ATOT  = 12 * R4_ASLAB;
__global__ void wconv_r4(const float* __restrict__ Wi, const float* __restrict__ Wh,
                         unsigned short* __restrict__ A2) {
    int idx = blockIdx.x * 256 + threadIdx.x;
    if (idx >= R4_ATOT) return;
    int ic = idx & 31; int r1 = idx >> 5;
    int tap = r1 % 9; int r2 = r1 / 9;
    int m = r2 & 15; int r3 = r2 >> 4;
    int gt = r3 % 3; int r4 = r3 / 3;
    int hg = r4 & 3; int ch = r4 >> 2;
    int o = gt * 64 + hg * 16 + m;
    float w = (ch == 0) ? Wi[(o * CIN + ic) * 9 + tap]
                        : Wh[(o * HID + (ch - 1) * 32 + ic) * 9 + tap];
    A2[idx] = f2bf(w);
}
__global__ __launch_bounds__(256, 2) void convgru_r4(
    const float* __restrict__ x, const unsigned short* __restrict__ A2,
    const float* hall, float* out, int t)
{
    __shared__ __align__(16) unsigned short tin[PR * PC * 40];
    __shared__ __align__(16) unsigned short Alr[48 * (F_AROWB / 2)];
    const int tid = threadIdx.x;
    const int lane = tid & 63, wave = tid >> 6;
    const int px = lane & 15, kl = lane >> 4;
    const int ty = blockIdx.x >> 2, tx = blockIdx.x & 3;
    const int hg = blockIdx.y, b = blockIdx.z;
    const int gy0 = ty * TR, gx0 = tx * TC;
    const int nch = (t > 0) ? 3 : 1;
    const float* hb = (t > 0) ? (hall + ((size_t)(b * T_ + t - 1)) * HID * HW) : nullptr;
    const float* xb = x + ((size_t)(b * T_ + t)) * CIN * HW;
    f32x4 accR[2] = {}, accZ[2] = {}, accNX[2] = {}, accNH[2] = {};
    float ireg[23]; bf16x8 areg[7];
    auto load_in = [&](int ch) {
        const float* src = (ch == 0) ? xb : (hb + (size_t)(ch - 1) * KCH * HW);
        #pragma unroll
        for (int j = 0; j < 23; ++j) {
            int e = tid + j * 256; float v = 0.f;
            if (e < PR * PC * KCH) {
                int ic = e / (PR * PC); int rem = e - ic * (PR * PC);
                int r = rem / PC, c = rem - r * PC;
                int gy = gy0 + r - 1, gx = gx0 + c - 1;
                if ((unsigned)gy < (unsigned)HH && (unsigned)gx < (unsigned)WW)
                    v = src[ic * HW + gy * WW + gx];
            }
            ireg[j] = v;
        }
    };
    auto load_Ar = [&](int ch) {
        const unsigned short* s = A2 + (size_t)(ch * 4 + hg) * R4_ASLAB;
        #pragma unroll
        for (int j = 0; j < 7; ++j) { int v = tid + j * 256; if (v < R4_AVEC) areg[j] = *(const bf16x8*)(s + v * 8); }
    };
    auto write_in = [&]() {
        #pragma unroll
        for (int j = 0; j < 23; ++j) {
            int e = tid + j * 256;
            if (e < PR * PC * KCH) {
                int ic = e / (PR * PC); int rem = e - ic * (PR * PC);
                int r = rem / PC, c = rem - r * PC;
                tin[(r * PC + c) * 40 + ic] = f2bf(ireg[j]);
            }
        }
    };
    auto write_Ar = [&]() {
        #pragma unroll
        for (int j = 0; j < 7; ++j) {
            int v = tid + j * 256;
            if (v < R4_AVEC) {
                int row = v / 36; int kb = (v - row * 36) * 16;
                char* dst = (char*)Alr + row * F_AROWB + (kb ^ ((row & 7) << 4));
                *(bf16x8*)dst = areg[j];
            }
        }
    };
    const int rb0 = ((wave * 2 + 0) * PC + px) * 40 + kl * 8;
    const int rb1 = rb0 + PC * 40;
    const int swA = (px & 7) << 4;
    auto compute = [&](bool isX) {
        #pragma unroll
        for (int tap = 0; tap < 9; ++tap) {
            const int dy = tap / 3, dx = tap - 3 * dy;
            const int toff = (dy * PC + dx) * 40;
            bf16x8 b0 = *(const bf16x8*)(tin + rb0 + toff);
            bf16x8 b1 = *(const bf16x8*)(tin + rb1 + toff);
            const char* ab = (const char*)Alr + px * F_AROWB + ((tap * 64 + kl * 16) ^ swA);
            bf16x8 ar = *(const bf16x8*)(ab);
            bf16x8 az = *(const bf16x8*)(ab + 16 * F_AROWB);
            bf16x8 an = *(const bf16x8*)(ab + 32 * F_AROWB);
            accR[0] = __builtin_amdgcn_mfma_f32_16x16x32_bf16(ar, b0, accR[0], 0, 0, 0);
            accR[1] = __builtin_amdgcn_mfma_f32_16x16x32_bf16(ar, b1, accR[1], 0, 0, 0);
            accZ[0] = __builtin_amdgcn_mfma_f32_16x16x32_bf16(az, b0, accZ[0], 0, 0, 0);
            accZ[1] = __builtin_amdgcn_mfma_f32_16x16x32_bf16(az, b1, accZ[1], 0, 0, 0);
            if (isX) {
                accNX[0] = __builtin_amdgcn_mfma_f32_16x16x32_bf16(an, b0, accNX[0], 0, 0, 0);
                accNX[1] = __builtin_amdgcn_mfma_f32_16x16x32_bf16(an, b1, accNX[1], 0, 0, 0);
            } else {
                accNH[0] = __builtin_amdgcn_mfma_f32_16x16x32_bf16(an, b0, accNH[0], 0, 0, 0);
                accNH[1] = __builtin_amdgcn_mfma_f32_16x16x32_bf16(an, b1, accNH[1], 0, 0, 0);
            }
        }
    };
    load_in(0); load_Ar(0); write_in(); write_Ar();
    __syncthreads();
    for (int ch = 0; ch < nch; ++ch) {
        if (ch + 1 < nch) { load_in(ch + 1); load_Ar(ch + 1); }
        compute(ch == 0);
        __syncthreads();
        if (ch + 1 < nch) { write_in(); write_Ar(); __syncthreads(); }
    }
    float* outp = out + ((size_t)(b * T_ + t)) * HID * HW;
    #pragma unroll
    for (int g = 0; g < 2; ++g) {
        int gy = gy0 + wave * 2 + g; int gx = gx0 + px;
        #pragma unroll
        for (int q = 0; q < 4; ++q) {
            int c = hg * 16 + kl * 4 + q;
            float sr = 1.f / (1.f + expf(-accR[g][q]));
            float sz = 1.f / (1.f + expf(-accZ[g][q]));
            float nn = tanhf(accNX[g][q] + sr * accNH[g][q]);
            float hv = hb ? hb[(size_t)c * HW + gy * WW + gx] : 0.f;
            outp[(size_t)c * HW + gy * WW + gx] = (1.f - sz) * nn + sz * hv;
        }
    }
}

extern "C" void kernel_launch(void* const* d_in, const int* in_sizes, int n_in,
                              void* d_out, int out_size, void* d_ws, size_t ws_size,
                              hipStream_t stream) {
    const float* x  = (const float*)d_in[0];
    const float* Wi = (const float*)d_in[1];
    const float* Wh = (const float*)d_in[2];
    float* out = (float*)d_out;

    if (ws_size >= WS_NEED_BYTES) {
        unsigned short* A2  = (unsigned short*)d_ws;
        unsigned short* xT  = A2 + XT_OFF;
        unsigned short* hT0 = A2 + HT_OFF;
        unsigned short* hT1 = hT0 + HTBUF_HW;
        int* flags = (int*)(A2 + FL_OFF);

        prep<<<PB_TOTAL, 256, 0, stream>>>(x, Wi, Wh, A2, xT, hT0);

        const unsigned short* xTc = xT;
        const unsigned short* A2c = A2;
        void* args[] = { (void*)&xTc, (void*)&A2c, (void*)&hT0, (void*)&hT1,
                         (void*)&flags, (void*)&out };
        hipError_t e = hipLaunchCooperativeKernel((void*)convgru_pers, dim3(32, 4, 4),
                                                  dim3(256, 1, 1), args, 0, stream);
        if (e != hipSuccess) {
            for (int t = 0; t < T_; ++t) {
                unsigned short* rd = (t & 1) ? hT1 : hT0;
                unsigned short* wr = (t & 1) ? hT0 : hT1;
                convgru_mfma<<<dim3(32, 4, 4), 256, 0, stream>>>(xT, A2, rd, wr, out, t);
            }
        }
    } else {
        unsigned short* A2 = (unsigned short*)d_ws;
        wconv_r4<<<(R4_ATOT + 255) / 256, 256, 0, stream>>>(Wi, Wh, A2);
        for (int t = 0; t < T_; ++t)
            convgru_r4<<<dim3(32, 4, 4), 256, 0, stream>>>(x, A2, out, out, t);
    }
}

// Round 14
// 208.713 us; speedup vs baseline: 10.9016x; 4.0130x over previous
//
#include <hip/hip_runtime.h>
#include <math.h>

typedef unsigned short us;
typedef __attribute__((ext_vector_type(8))) short bf16x8;
typedef __attribute__((ext_vector_type(4))) float f32x4;

// Problem dims
constexpr int B_  = 4;
constexpr int T_  = 16;
constexpr int CIN = 32;
constexpr int HID = 64;
constexpr int HH  = 64;
constexpr int WW  = 64;
constexpr int HW  = HH * WW;

// ---------------- config ----------------
constexpr int CSL = 40;                       // channel slots per pixel (80B)
constexpr int ASLAB_HW = 3 * 36 * 16 * 8;     // 13824 hw per (chunk,hg) slab
constexpr int ATOTAL   = 12 * ASLAB_HW;
constexpr int PD       = 68;                  // padded image dim (2-px zero ring)
constexpr int PROW_HW  = PD * CSL;            // 2720
constexpr int PIMG_HW  = PD * PROW_HW;        // 184960
// pair-kernel tiles: output 4x16; step-A region 6x18; staging region 8x20
constexpr int T20_HW = 8 * 20 * CSL;          // 6400
constexpr int T18_HW = 6 * 18 * CSL;          // 4320
constexpr int T20_GR = T20_HW / 8;            // 800
constexpr int T18_GR = T18_HW / 8;            // 540

// ws layout (halfword offsets)
constexpr size_t XT_OFF   = (size_t)ATOTAL;
constexpr size_t XT_HW    = (size_t)64 * PIMG_HW;
constexpr size_t HT_OFF   = XT_OFF + XT_HW;
constexpr size_t HTBUF_HW = (size_t)8 * PIMG_HW;   // [b4][chunk2] images
constexpr size_t WS_NEED_BYTES = (HT_OFF + 2 * HTBUF_HW) * 2;

// fused prepass block ranges
constexpr int PB_XFILL = PD * 64;                   // 4352
constexpr int PB_WCONV = (ATOTAL + 255) / 256;      // 648
constexpr int HZ_GRAN  = (int)(2 * HTBUF_HW / 8);   // 369920
constexpr int PB_HZERO = (HZ_GRAN + 255) / 256;
constexpr int PB_TOTAL = PB_XFILL + PB_WCONV + PB_HZERO;

#define GLOAD_LDS16(gsrc, ldst) \
  __builtin_amdgcn_global_load_lds((const __attribute__((address_space(1))) void*)(gsrc), \
                                   (__attribute__((address_space(3))) void*)(ldst), 16, 0, 0)
#define MFMA_B(d, A, Bv) d = __builtin_amdgcn_mfma_f32_16x16x32_bf16(A, Bv, d, 0, 0, 0)

__device__ inline us f2bf(float f) {
    union { float f; unsigned u; } v; v.f = f;
    return (us)((v.u + 0x7FFFu + ((v.u >> 16) & 1u)) >> 16);
}
__device__ inline float bf2f(us h) {
    union { unsigned u; float f; } v; v.u = (unsigned)h << 16; return v.f;
}

// ---- fused prepass: xfill(68-pad) | wconv | hzero ----
__global__ void prep(const float* __restrict__ x,
                     const float* __restrict__ Wi, const float* __restrict__ Wh,
                     us* __restrict__ A2, us* __restrict__ xT, us* __restrict__ hT) {
    __shared__ float lds[64 * 41];
    const int bid = blockIdx.x;

    if (bid < PB_XFILL) {
        const int riT = bid % PD;      // 0..67
        const int bt  = bid / PD;
        us* dst = xT + (size_t)bt * PIMG_HW + (size_t)riT * PROW_HW;
        const bool interior = (riT >= 2 && riT <= 65);
        if (interior) {
            const float* src = x + (size_t)bt * 32 * HW + (riT - 2) * WW;
            const int p = threadIdx.x & 63;
            #pragma unroll
            for (int j = 0; j < 8; ++j) {
                int c = j * 4 + (threadIdx.x >> 6);
                lds[p * 41 + c] = src[c * HW + p];
            }
        }
        __syncthreads();
        for (int g = threadIdx.x; g < PROW_HW / 8; g += 256) {  // 340 granules
            bf16x8 vv;
            #pragma unroll
            for (int k = 0; k < 8; ++k) {
                int off = g * 8 + k;
                int px = off / CSL, slot = off - px * CSL;
                float v = 0.f;
                if (interior && slot < 32 && px >= 2 && px <= 65)
                    v = lds[(px - 2) * 41 + slot];
                vv[k] = (short)f2bf(v);
            }
            *(bf16x8*)(dst + g * 8) = vv;
        }
    } else if (bid < PB_XFILL + PB_WCONV) {
        int idx = (bid - PB_XFILL) * 256 + threadIdx.x;
        if (idx >= ATOTAL) return;
        int ic  = idx & 31;
        int r1  = idx >> 5;
        int tap = r1 % 9;
        int r2  = r1 / 9;
        int m   = r2 & 15;
        int r3  = r2 >> 4;
        int gt  = r3 % 3;
        int r4  = r3 / 3;
        int hg  = r4 & 3;
        int ch  = r4 >> 2;
        int o   = gt * 64 + hg * 16 + m;
        float w = (ch == 0) ? Wi[(o * CIN + ic) * 9 + tap]
                            : Wh[(o * HID + (ch - 1) * 32 + ic) * 9 + tap];
        size_t dst = (size_t)(ch * 4 + hg) * ASLAB_HW
                   + ((size_t)(gt * 36 + tap * 4 + (ic >> 3)) * 16 + m) * 8 + (ic & 7);
        A2[dst] = f2bf(w);
    } else {
        int i = (bid - PB_XFILL - PB_WCONV) * 256 + threadIdx.x;
        if (i < HZ_GRAN) ((f32x4*)hT)[i] = f32x4{0.f, 0.f, 0.f, 0.f};
    }
}

// ========== pair kernel: steps t0 and t0+1, no inter-block sync ==========
// grid (64 tiles, 1, 4 b), 512 thr (8 waves = 4 hg x 2 sg). Output tile 4x16 x 64ch.
__global__ __launch_bounds__(512, 2) void convgru_pair(
    const us* __restrict__ xT, const us* __restrict__ A2g,
    const us* __restrict__ hTrd, us* __restrict__ hTwr,
    float* __restrict__ out, int t0)
{
    __shared__ __align__(16) us t20x[T20_HW], t20L[T20_HW], t20H[T20_HW]; // 3x12.8KB
    __shared__ __align__(16) us t18x[T18_HW], t18L[T18_HW], t18H[T18_HW]; // 3x8.64KB

    const int tid = threadIdx.x, lane = tid & 63, wave = tid >> 6;
    const int hg = wave & 3, sg = wave >> 2;
    const int px = lane & 15, kl = lane >> 4;
    const int tile = blockIdx.x, ty = tile >> 2, tx = tile & 3, b = blockIdx.z;
    const int gy0 = ty * 4, gx0 = tx * 16;

    auto st20 = [&](const us* img, us* dst) {
        #pragma unroll
        for (int j = 0; j < 2; ++j) {
            int G = tid + j * 512;
            if (G < T20_GR) {
                int r = G / 100, w = G - 100 * r;
                GLOAD_LDS16(img + (size_t)((gy0 + r) * PD + gx0) * CSL + w * 8, dst + G * 8);
            }
        }
    };
    auto st18 = [&](const us* img, us* dst) {
        #pragma unroll
        for (int j = 0; j < 2; ++j) {
            int G = tid + j * 512;
            if (G < T18_GR) {
                int r = G / 90, w = G - 90 * r;
                GLOAD_LDS16(img + (size_t)((gy0 + 1 + r) * PD + gx0 + 1) * CSL + w * 8, dst + G * 8);
            }
        }
    };

    const us* A0p = A2g + (size_t)(0 * 4 + hg) * ASLAB_HW + lane * 8;
    const us* A1p = A2g + (size_t)(1 * 4 + hg) * ASLAB_HW + lane * 8;
    const us* A2p = A2g + (size_t)(2 * 4 + hg) * ASLAB_HW + lane * 8;

    bf16x8 a[27];
    auto loadA = [&](const us* p) {
        #pragma unroll
        for (int i = 0; i < 27; ++i)
            a[i] = *(const bf16x8*)(p + (size_t)((i / 9) * 36 + (i % 9) * 4) * 128);
    };

    // step-A unit tables: (row-pair, col-offset) covering the 6x18 region
    const int rp_t[2][3] = {{0, 0, 1}, {1, 2, 2}};
    const int co_t[2][3] = {{0, 2, 0}, {2, 0, 2}};

    f32x4 aR[3][2], aZ[3][2], aNX[3][2], aNH[3][2];
    auto zacc = [&]() {
        #pragma unroll
        for (int u = 0; u < 3; ++u)
            #pragma unroll
            for (int g = 0; g < 2; ++g) {
                aR[u][g] = f32x4{0.f,0.f,0.f,0.f}; aZ[u][g] = f32x4{0.f,0.f,0.f,0.f};
                aNX[u][g] = f32x4{0.f,0.f,0.f,0.f}; aNH[u][g] = f32x4{0.f,0.f,0.f,0.f};
            }
    };

    // one K-chunk of step A: 3 units, source = 8x20 tile
    auto phaseA = [&](const us* tb, bool isX, const us* nextA) {
        #pragma unroll
        for (int u = 0; u < 3; ++u) {
            const int rp = rp_t[sg][u], co = co_t[sg][u];
            const int rbu = (2 * rp * 20 + co + px) * CSL + kl * 8;
            const bool pf = (u == 2) && (nextA != nullptr);
            #pragma unroll
            for (int dx = 0; dx < 3; ++dx) {
                bf16x8 P[4];
                #pragma unroll
                for (int r = 0; r < 4; ++r)
                    P[r] = *(const bf16x8*)(tb + rbu + (r * 20 + dx) * CSL);
                #pragma unroll
                for (int dy = 0; dy < 3; ++dy) {
                    const int tap = dy * 3 + dx;
                    bf16x8 b0 = P[dy], b1 = P[dy + 1];
                    bf16x8 ar = a[tap], az = a[9 + tap], an = a[18 + tap];
                    if (pf) {
                        a[tap]      = *(const bf16x8*)(nextA + (size_t)(0 * 36 + tap * 4) * 128);
                        a[9 + tap]  = *(const bf16x8*)(nextA + (size_t)(1 * 36 + tap * 4) * 128);
                        a[18 + tap] = *(const bf16x8*)(nextA + (size_t)(2 * 36 + tap * 4) * 128);
                    }
                    MFMA_B(aR[u][0], ar, b0); MFMA_B(aR[u][1], ar, b1);
                    MFMA_B(aZ[u][0], az, b0); MFMA_B(aZ[u][1], az, b1);
                    if (isX) { MFMA_B(aNX[u][0], an, b0); MFMA_B(aNX[u][1], an, b1); }
                    else     { MFMA_B(aNH[u][0], an, b0); MFMA_B(aNH[u][1], an, b1); }
                }
            }
        }
    };

    // one K-chunk of step B: 1 unit (acc slot 0), source = 6x18 tile
    auto phaseB = [&](const us* tb, bool isX, const us* nextA) {
        const int rbu = (2 * sg * 18 + px) * CSL + kl * 8;
        #pragma unroll
        for (int dx = 0; dx < 3; ++dx) {
            bf16x8 P[4];
            #pragma unroll
            for (int r = 0; r < 4; ++r)
                P[r] = *(const bf16x8*)(tb + rbu + (r * 18 + dx) * CSL);
            #pragma unroll
            for (int dy = 0; dy < 3; ++dy) {
                const int tap = dy * 3 + dx;
                bf16x8 b0 = P[dy], b1 = P[dy + 1];
                bf16x8 ar = a[tap], az = a[9 + tap], an = a[18 + tap];
                if (nextA) {
                    a[tap]      = *(const bf16x8*)(nextA + (size_t)(0 * 36 + tap * 4) * 128);
                    a[9 + tap]  = *(const bf16x8*)(nextA + (size_t)(1 * 36 + tap * 4) * 128);
                    a[18 + tap] = *(const bf16x8*)(nextA + (size_t)(2 * 36 + tap * 4) * 128);
                }
                MFMA_B(aR[0][0], ar, b0); MFMA_B(aR[0][1], ar, b1);
                MFMA_B(aZ[0][0], az, b0); MFMA_B(aZ[0][1], az, b1);
                if (isX) { MFMA_B(aNX[0][0], an, b0); MFMA_B(aNX[0][1], an, b1); }
                else     { MFMA_B(aNH[0][0], an, b0); MFMA_B(aNH[0][1], an, b1); }
            }
        }
    };

    const int c0 = hg * 16 + kl * 4;
    const int slot = c0 & 31;

    // ---- stage everything, one barrier ----
    const us* xs0 = xT + (size_t)(b * T_ + t0) * PIMG_HW;
    const us* xs1 = xT + (size_t)(b * T_ + t0 + 1) * PIMG_HW;
    st20(xs0, t20x);
    st18(xs1, t18x);
    if (t0 > 0) {
        st20(hTrd + (size_t)(b * 2 + 0) * PIMG_HW, t20L);
        st20(hTrd + (size_t)(b * 2 + 1) * PIMG_HW, t20H);
    }
    loadA(A0p);
    __syncthreads();

    // ---- step A: h_{t0} on the 6x18 region ----
    zacc();
    if (t0 > 0) {
        phaseA(t20x, true,  A1p);
        phaseA(t20L, false, A2p);
        phaseA(t20H, false, A0p);   // cycle back to A(0) for step B's x-chunk
    } else {
        phaseA(t20x, true, nullptr); // a[] stays A(0)
    }

    { // epilogue A: gates -> h_t to LDS (+ inner 4x16 to out)
        float* outp = out + ((size_t)(b * T_ + t0)) * HID * HW;
        us* hlds = (hg < 2) ? t18L : t18H;
        const us* h20 = (hg < 2) ? t20L : t20H;
        #pragma unroll
        for (int u = 0; u < 3; ++u) {
            const int rp = rp_t[sg][u], co = co_t[sg][u];
            #pragma unroll
            for (int g = 0; g < 2; ++g) {
                int rr = 2 * rp + g;        // region row 0..5
                int cc = co + px;           // region col 0..17
                int gy = gy0 - 1 + rr, gx = gx0 - 1 + cc;
                bool inimg = ((unsigned)gy < 64u) && ((unsigned)gx < 64u);
                float hvf[4] = {0.f, 0.f, 0.f, 0.f};
                if (t0 > 0) {
                    const us* hp = h20 + (size_t)((rr + 1) * 20 + cc + 1) * CSL + slot;
                    #pragma unroll
                    for (int q = 0; q < 4; ++q) hvf[q] = bf2f(hp[q]);
                }
                us hv[4];
                bool inner = (rr >= 1 && rr <= 4 && cc >= 1 && cc <= 16);
                #pragma unroll
                for (int q = 0; q < 4; ++q) {
                    float sr = __builtin_amdgcn_rcpf(1.f + __expf(-aR[u][g][q]));
                    float sz = __builtin_amdgcn_rcpf(1.f + __expf(-aZ[u][g][q]));
                    float ag = aNX[u][g][q] + sr * aNH[u][g][q];
                    float nn = 2.f * __builtin_amdgcn_rcpf(1.f + __expf(-2.f * ag)) - 1.f;
                    float hn = nn + sz * (hvf[q] - nn);
                    hn = inimg ? hn : 0.f;
                    hv[q] = f2bf(hn);
                    if (inner) outp[(size_t)(c0 + q) * HW + gy * WW + gx] = hn;
                }
                *(uint2*)(hlds + (size_t)(rr * 18 + cc) * CSL + slot) = *(const uint2*)hv;
            }
        }
    }
    __syncthreads();   // h_t tile complete

    // ---- step B: h_{t0+1} on the 4x16 output tile ----
    zacc();
    phaseB(t18x, true,  A1p);
    phaseB(t18L, false, A2p);
    phaseB(t18H, false, nullptr);

    { // epilogue B: out + hT global (padded, bf16)
        float* outp = out + ((size_t)(b * T_ + t0 + 1)) * HID * HW;
        const us* hlds = (hg < 2) ? t18L : t18H;
        #pragma unroll
        for (int g = 0; g < 2; ++g) {
            int orow = 2 * sg + g;          // 0..3
            int gy = gy0 + orow, gx = gx0 + px;
            float hvf[4];
            const us* hp = hlds + (size_t)((orow + 1) * 18 + (px + 1)) * CSL + slot;
            #pragma unroll
            for (int q = 0; q < 4; ++q) hvf[q] = bf2f(hp[q]);
            us hv[4];
            #pragma unroll
            for (int q = 0; q < 4; ++q) {
                float sr = __builtin_amdgcn_rcpf(1.f + __expf(-aR[0][g][q]));
                float sz = __builtin_amdgcn_rcpf(1.f + __expf(-aZ[0][g][q]));
                float ag = aNX[0][g][q] + sr * aNH[0][g][q];
                float nn = 2.f * __builtin_amdgcn_rcpf(1.f + __expf(-2.f * ag)) - 1.f;
                float hn = nn + sz * (hvf[q] - nn);
                outp[(size_t)(c0 + q) * HW + gy * WW + gx] = hn;
                hv[q] = f2bf(hn);
            }
            us* hd = hTwr + (size_t)(b * 2 + (c0 >> 5)) * PIMG_HW
                   + (size_t)((gy + 2) * PD + (gx + 2)) * CSL + slot;
            *(uint2*)hd = *(const uint2*)hv;
        }
    }
}

// ================= round-4 fallback (tiny ws) =================
constexpr int F_AROWB = 640;
constexpr int R4_ASLAB = 48 * 9 * 32;
constexpr int R4_AVEC  = R4_ASLAB / 8;
constexpr int R4_ATOT  = 12 * R4_ASLAB;
constexpr int FPR = 10, FPC = 18;
__global__ void wconv_r4(const float* __restrict__ Wi, const float* __restrict__ Wh,
                         us* __restrict__ A2) {
    int idx = blockIdx.x * 256 + threadIdx.x;
    if (idx >= R4_ATOT) return;
    int ic = idx & 31; int r1 = idx >> 5;
    int tap = r1 % 9; int r2 = r1 / 9;
    int m = r2 & 15; int r3 = r2 >> 4;
    int gt = r3 % 3; int r4 = r3 / 3;
    int hg = r4 & 3; int ch = r4 >> 2;
    int o = gt * 64 + hg * 16 + m;
    float w = (ch == 0) ? Wi[(o * CIN + ic) * 9 + tap]
                        : Wh[(o * HID + (ch - 1) * 32 + ic) * 9 + tap];
    A2[idx] = f2bf(w);
}
__global__ __launch_bounds__(256, 2) void convgru_r4(
    const float* __restrict__ x, const us* __restrict__ A2,
    const float* hall, float* out, int t)
{
    __shared__ __align__(16) us tin[FPR * FPC * 40];
    __shared__ __align__(16) us Alr[48 * (F_AROWB / 2)];
    const int tid = threadIdx.x;
    const int lane = tid & 63, wave = tid >> 6;
    const int px = lane & 15, kl = lane >> 4;
    const int ty = blockIdx.x >> 2, tx = blockIdx.x & 3;
    const int hg = blockIdx.y, b = blockIdx.z;
    const int gy0 = ty * 8, gx0 = tx * 16;
    const int nch = (t > 0) ? 3 : 1;
    const float* hb = (t > 0) ? (hall + ((size_t)(b * T_ + t - 1)) * HID * HW) : nullptr;
    const float* xb = x + ((size_t)(b * T_ + t)) * CIN * HW;
    f32x4 accR[2] = {}, accZ[2] = {}, accNX[2] = {}, accNH[2] = {};
    float ireg[23]; bf16x8 areg[7];
    auto load_in = [&](int ch) {
        const float* src = (ch == 0) ? xb : (hb + (size_t)(ch - 1) * 32 * HW);
        #pragma unroll
        for (int j = 0; j < 23; ++j) {
            int e = tid + j * 256; float v = 0.f;
            if (e < FPR * FPC * 32) {
                int ic = e / (FPR * FPC); int rem = e - ic * (FPR * FPC);
                int r = rem / FPC, c = rem - r * FPC;
                int gy = gy0 + r - 1, gx = gx0 + c - 1;
                if ((unsigned)gy < (unsigned)HH && (unsigned)gx < (unsigned)WW)
                    v = src[ic * HW + gy * WW + gx];
            }
            ireg[j] = v;
        }
    };
    auto load_Ar = [&](int ch) {
        const us* s = A2 + (size_t)(ch * 4 + hg) * R4_ASLAB;
        #pragma unroll
        for (int j = 0; j < 7; ++j) { int v = tid + j * 256; if (v < R4_AVEC) areg[j] = *(const bf16x8*)(s + v * 8); }
    };
    auto write_in = [&]() {
        #pragma unroll
        for (int j = 0; j < 23; ++j) {
            int e = tid + j * 256;
            if (e < FPR * FPC * 32) {
                int ic = e / (FPR * FPC); int rem = e - ic * (FPR * FPC);
                int r = rem / FPC, c = rem - r * FPC;
                tin[(r * FPC + c) * 40 + ic] = f2bf(ireg[j]);
            }
        }
    };
    auto write_Ar = [&]() {
        #pragma unroll
        for (int j = 0; j < 7; ++j) {
            int v = tid + j * 256;
            if (v < R4_AVEC) {
                int row = v / 36; int kb = (v - row * 36) * 16;
                char* dst = (char*)Alr + row * F_AROWB + (kb ^ ((row & 7) << 4));
                *(bf16x8*)dst = areg[j];
            }
        }
    };
    const int rb0 = ((wave * 2 + 0) * FPC + px) * 40 + kl * 8;
    const int rb1 = rb0 + FPC * 40;
    const int swA = (px & 7) << 4;
    auto compute = [&](bool isX) {
        #pragma unroll
        for (int tap = 0; tap < 9; ++tap) {
            const int dy = tap / 3, dx = tap - 3 * dy;
            const int toff = (dy * FPC + dx) * 40;
            bf16x8 b0 = *(const bf16x8*)(tin + rb0 + toff);
            bf16x8 b1 = *(const bf16x8*)(tin + rb1 + toff);
            const char* ab = (const char*)Alr + px * F_AROWB + ((tap * 64 + kl * 16) ^ swA);
            bf16x8 ar = *(const bf16x8*)(ab);
            bf16x8 az = *(const bf16x8*)(ab + 16 * F_AROWB);
            bf16x8 an = *(const bf16x8*)(ab + 32 * F_AROWB);
            MFMA_B(accR[0], ar, b0); MFMA_B(accR[1], ar, b1);
            MFMA_B(accZ[0], az, b0); MFMA_B(accZ[1], az, b1);
            if (isX) { MFMA_B(accNX[0], an, b0); MFMA_B(accNX[1], an, b1); }
            else     { MFMA_B(accNH[0], an, b0); MFMA_B(accNH[1], an, b1); }
        }
    };
    load_in(0); load_Ar(0); write_in(); write_Ar();
    __syncthreads();
    for (int ch = 0; ch < nch; ++ch) {
        if (ch + 1 < nch) { load_in(ch + 1); load_Ar(ch + 1); }
        compute(ch == 0);
        __syncthreads();
        if (ch + 1 < nch) { write_in(); write_Ar(); __syncthreads(); }
    }
    float* outp = out + ((size_t)(b * T_ + t)) * HID * HW;
    #pragma unroll
    for (int g = 0; g < 2; ++g) {
        int gy = gy0 + wave * 2 + g; int gx = gx0 + px;
        #pragma unroll
        for (int q = 0; q < 4; ++q) {
            int c = hg * 16 + kl * 4 + q;
            float sr = 1.f / (1.f + expf(-accR[g][q]));
            float sz = 1.f / (1.f + expf(-accZ[g][q]));
            float nn = tanhf(accNX[g][q] + sr * accNH[g][q]);
            float hv = hb ? hb[(size_t)c * HW + gy * WW + gx] : 0.f;
            outp[(size_t)c * HW + gy * WW + gx] = (1.f - sz) * nn + sz * hv;
        }
    }
}

extern "C" void kernel_launch(void* const* d_in, const int* in_sizes, int n_in,
                              void* d_out, int out_size, void* d_ws, size_t ws_size,
                              hipStream_t stream) {
    const float* x  = (const float*)d_in[0];
    const float* Wi = (const float*)d_in[1];
    const float* Wh = (const float*)d_in[2];
    float* out = (float*)d_out;

    if (ws_size >= WS_NEED_BYTES) {
        us* A2  = (us*)d_ws;
        us* xT  = A2 + XT_OFF;
        us* hT0 = A2 + HT_OFF;
        us* hT1 = hT0 + HTBUF_HW;

        prep<<<PB_TOTAL, 256, 0, stream>>>(x, Wi, Wh, A2, xT, hT0);
        for (int p = 0; p < T_ / 2; ++p) {
            us* rd = (p & 1) ? hT1 : hT0;
            us* wr = (p & 1) ? hT0 : hT1;
            convgru_pair<<<dim3(64, 1, 4), 512, 0, stream>>>(xT, A2, rd, wr, out, 2 * p);
        }
    } else {
        us* A2 = (us*)d_ws;
        wconv_r4<<<(R4_ATOT + 255) / 256, 256, 0, stream>>>(Wi, Wh, A2);
        for (int t = 0; t < T_; ++t)
            convgru_r4<<<dim3(32, 4, 4), 256, 0, stream>>>(x, A2, out, out, t);
    }
}

// Round 15
// 152.297 us; speedup vs baseline: 14.9399x; 1.3704x over previous
//
#include <hip/hip_runtime.h>
#include <math.h>

typedef unsigned short us;
typedef __attribute__((ext_vector_type(8))) short bf16x8;
typedef __attribute__((ext_vector_type(4))) float f32x4;

// Problem dims
constexpr int B_  = 4;
constexpr int T_  = 16;
constexpr int CIN = 32;
constexpr int HID = 64;
constexpr int HH  = 64;
constexpr int WW  = 64;
constexpr int HW  = HH * WW;

// ---------------- config ----------------
constexpr int CSL = 40;                       // channel slots per pixel (80B)
constexpr int KCH = 32;
constexpr int ASLAB_HW = 3 * 36 * 16 * 8;     // 13824 hw per (chunk,hg) slab
constexpr int ATOTAL   = 12 * ASLAB_HW;
constexpr int ROW_HW   = 66 * CSL;            // 2640 hw per padded row
constexpr int PIMG_HW  = 66 * ROW_HW;         // padded image (1-px ring)
// step tile: out 4x16; halo 6x18
constexpr int T6_HW  = 6 * 18 * CSL;          // 4320 hw (8640 B)
constexpr int T6_GR  = T6_HW / 8;             // 540 granules

// ws layout (halfword offsets)
constexpr size_t XT_OFF   = (size_t)ATOTAL;
constexpr size_t XT_HW    = (size_t)64 * PIMG_HW;
constexpr size_t HT_OFF   = XT_OFF + XT_HW;
constexpr size_t HTBUF_HW = (size_t)8 * PIMG_HW;   // [b4][chunk2] images
constexpr size_t WS_NEED_BYTES = (HT_OFF + 2 * HTBUF_HW) * 2;

// fused prepass block ranges
constexpr int PB_XFILL = 66 * 64;
constexpr int PB_WCONV = (ATOTAL + 255) / 256;
constexpr int HZ_GRAN  = (int)(2 * HTBUF_HW / 8);
constexpr int PB_HZERO = (HZ_GRAN + 255) / 256;
constexpr int PB_TOTAL = PB_XFILL + PB_WCONV + PB_HZERO;

#define GLOAD_LDS16(gsrc, ldst) \
  __builtin_amdgcn_global_load_lds((const __attribute__((address_space(1))) void*)(gsrc), \
                                   (__attribute__((address_space(3))) void*)(ldst), 16, 0, 0)
#define MFMA_B(d, A, Bv) d = __builtin_amdgcn_mfma_f32_16x16x32_bf16(A, Bv, d, 0, 0, 0)

__device__ inline us f2bf(float f) {
    union { float f; unsigned u; } v; v.f = f;
    return (us)((v.u + 0x7FFFu + ((v.u >> 16) & 1u)) >> 16);
}
__device__ inline float bf2f(us h) {
    union { unsigned u; float f; } v; v.u = (unsigned)h << 16; return v.f;
}

// ---- fused prepass: xfill | wconv | hzero (identical to r11) ----
__global__ void prep(const float* __restrict__ x,
                     const float* __restrict__ Wi, const float* __restrict__ Wh,
                     us* __restrict__ A2, us* __restrict__ xT, us* __restrict__ hT) {
    __shared__ float lds[64 * 41];
    const int bid = blockIdx.x;

    if (bid < PB_XFILL) {
        const int riT = bid % 66;
        const int bt  = bid / 66;
        us* dst = xT + (size_t)bt * PIMG_HW + (size_t)riT * ROW_HW;
        const bool interior = (riT >= 1 && riT <= 64);
        if (interior) {
            const float* src = x + (size_t)bt * 32 * HW + (riT - 1) * WW;
            const int p = threadIdx.x & 63;
            #pragma unroll
            for (int j = 0; j < 8; ++j) {
                int c = j * 4 + (threadIdx.x >> 6);
                lds[p * 41 + c] = src[c * HW + p];
            }
        }
        __syncthreads();
        for (int g = threadIdx.x; g < ROW_HW / 8; g += 256) {
            bf16x8 vv;
            #pragma unroll
            for (int k = 0; k < 8; ++k) {
                int off = g * 8 + k;
                int px = off / CSL, slot = off - px * CSL;
                float v = 0.f;
                if (interior && slot < 32 && px >= 1 && px <= 64)
                    v = lds[(px - 1) * 41 + slot];
                vv[k] = (short)f2bf(v);
            }
            *(bf16x8*)(dst + g * 8) = vv;
        }
    } else if (bid < PB_XFILL + PB_WCONV) {
        int idx = (bid - PB_XFILL) * 256 + threadIdx.x;
        if (idx >= ATOTAL) return;
        int ic  = idx & 31;
        int r1  = idx >> 5;
        int tap = r1 % 9;
        int r2  = r1 / 9;
        int m   = r2 & 15;
        int r3  = r2 >> 4;
        int gt  = r3 % 3;
        int r4  = r3 / 3;
        int hg  = r4 & 3;
        int ch  = r4 >> 2;
        int o   = gt * 64 + hg * 16 + m;
        float w = (ch == 0) ? Wi[(o * CIN + ic) * 9 + tap]
                            : Wh[(o * HID + (ch - 1) * 32 + ic) * 9 + tap];
        size_t dst = (size_t)(ch * 4 + hg) * ASLAB_HW
                   + ((size_t)(gt * 36 + tap * 4 + (ic >> 3)) * 16 + m) * 8 + (ic & 7);
        A2[dst] = f2bf(w);
    } else {
        int i = (bid - PB_XFILL - PB_WCONV) * 256 + threadIdx.x;
        if (i < HZ_GRAN) ((f32x4*)hT)[i] = f32x4{0.f, 0.f, 0.f, 0.f};
    }
}

// ---- step kernel: tile 4x16 x 64ch, 4 waves (one per hg), 2 units/wave ----
// grid (64 tiles, 1, 4 b), 256 thr, 1 block/CU.
__global__ __launch_bounds__(256, 1) void convgru_step(
    const us* __restrict__ xT, const us* __restrict__ A2,
    const us* __restrict__ hTrd, us* __restrict__ hTwr,
    float* __restrict__ out, int t)
{
    __shared__ __align__(16) us t0s[T6_HW];  // x tile
    __shared__ __align__(16) us t1s[T6_HW];  // h ch 0-31
    __shared__ __align__(16) us t2s[T6_HW];  // h ch 32-63

    const int tid  = threadIdx.x;
    const int lane = tid & 63, hg = tid >> 6;   // wave = hg
    const int px   = lane & 15, kl = lane >> 4;
    const int tile = blockIdx.x, ty = tile >> 2, tx = tile & 3, b = blockIdx.z;
    const int gy0 = ty * 4, gx0 = tx * 16;
    const int rowbase = gy0 * 66 + gx0;         // halo origin in padded image

    f32x4 aR[2][2], aZ[2][2], aNX[2][2], aNH[2][2];
    #pragma unroll
    for (int u = 0; u < 2; ++u)
        #pragma unroll
        for (int g = 0; g < 2; ++g) {
            aR[u][g] = f32x4{0.f,0.f,0.f,0.f}; aZ[u][g] = f32x4{0.f,0.f,0.f,0.f};
            aNX[u][g] = f32x4{0.f,0.f,0.f,0.f}; aNH[u][g] = f32x4{0.f,0.f,0.f,0.f};
        }
    bf16x8 a[27];

    auto stage_tin = [&](const us* src, us* dst) {
        #pragma unroll
        for (int j = 0; j < 3; ++j) {
            int G = tid + j * 256;
            if (G < T6_GR) {
                int r = G / 90, w = G - 90 * r;   // 90 granules per halo row
                GLOAD_LDS16(src + (size_t)(rowbase + r * 66) * CSL + w * 8, dst + G * 8);
            }
        }
    };
    auto regA = [&](int ch) {
        const us* s = A2 + (size_t)(ch * 4 + hg) * ASLAB_HW + lane * 8;
        #pragma unroll
        for (int i = 0; i < 27; ++i)
            a[i] = *(const bf16x8*)(s + (size_t)((i / 9) * 36 + (i % 9) * 4) * 128);
    };

    const int rbase = px * CSL + kl * 8;

    auto compute = [&](const us* tb, bool isX, const us* nextA) {
        #pragma unroll
        for (int dx = 0; dx < 3; ++dx) {
            bf16x8 P[6];
            #pragma unroll
            for (int r = 0; r < 6; ++r)
                P[r] = *(const bf16x8*)(tb + (r * 18 + dx) * CSL + rbase);
            #pragma unroll
            for (int dy = 0; dy < 3; ++dy) {
                const int tap = dy * 3 + dx;
                bf16x8 ar = a[tap], az = a[9 + tap], an = a[18 + tap];
                if (nextA) {   // pipelined reload of this tap's fragments
                    a[tap]      = *(const bf16x8*)(nextA + (size_t)(0 * 36 + tap * 4) * 128);
                    a[9 + tap]  = *(const bf16x8*)(nextA + (size_t)(1 * 36 + tap * 4) * 128);
                    a[18 + tap] = *(const bf16x8*)(nextA + (size_t)(2 * 36 + tap * 4) * 128);
                }
                #pragma unroll
                for (int u = 0; u < 2; ++u) {
                    bf16x8 b0 = P[2 * u + dy], b1 = P[2 * u + dy + 1];
                    MFMA_B(aR[u][0], ar, b0); MFMA_B(aR[u][1], ar, b1);
                    MFMA_B(aZ[u][0], az, b0); MFMA_B(aZ[u][1], az, b1);
                    if (isX) { MFMA_B(aNX[u][0], an, b0); MFMA_B(aNX[u][1], an, b1); }
                    else     { MFMA_B(aNH[u][0], an, b0); MFMA_B(aNH[u][1], an, b1); }
                }
            }
        }
    };

    // ---- schedule: all DMA staging up front, ONE barrier ----
    stage_tin(xT + (size_t)(b * T_ + t) * PIMG_HW, t0s);
    if (t > 0) {
        stage_tin(hTrd + (size_t)(b * 2 + 0) * PIMG_HW, t1s);
        stage_tin(hTrd + (size_t)(b * 2 + 1) * PIMG_HW, t2s);
    }
    regA(0);
    __syncthreads();

    const us* A1p = (t > 0) ? A2 + (size_t)(1 * 4 + hg) * ASLAB_HW + lane * 8 : nullptr;
    const us* A2p = (t > 0) ? A2 + (size_t)(2 * 4 + hg) * ASLAB_HW + lane * 8 : nullptr;

    compute(t0s, true, A1p);
    if (t > 0) {
        compute(t1s, false, A2p);
        compute(t2s, false, nullptr);
    }

    // ---- epilogue ----
    float* outp = out + ((size_t)(b * T_ + t)) * HID * HW;
    const int c0   = hg * 16 + kl * 4;
    const int slot = c0 & 31;
    const us* hbuf = (hg < 2) ? t1s : t2s;
    #pragma unroll
    for (int u = 0; u < 2; ++u) {
        #pragma unroll
        for (int g = 0; g < 2; ++g) {
            int orow = 2 * u + g;                 // 0..3
            int gy = gy0 + orow, gx = gx0 + px;
            float hvf[4] = {0.f, 0.f, 0.f, 0.f};
            if (t > 0) {
                const us* hp = hbuf + (size_t)((orow + 1) * 18 + (px + 1)) * CSL + slot;
                #pragma unroll
                for (int q = 0; q < 4; ++q) hvf[q] = bf2f(hp[q]);
            }
            us hv[4];
            #pragma unroll
            for (int q = 0; q < 4; ++q) {
                float sr = __builtin_amdgcn_rcpf(1.f + __expf(-aR[u][g][q]));
                float sz = __builtin_amdgcn_rcpf(1.f + __expf(-aZ[u][g][q]));
                float ag = aNX[u][g][q] + sr * aNH[u][g][q];
                float nn = 2.f * __builtin_amdgcn_rcpf(1.f + __expf(-2.f * ag)) - 1.f;
                float hn = nn + sz * (hvf[q] - nn);
                outp[(size_t)(c0 + q) * HW + gy * WW + gx] = hn;
                hv[q] = f2bf(hn);
            }
            us* hd = hTwr + (size_t)(b * 2 + (c0 >> 5)) * PIMG_HW
                   + (size_t)((gy + 1) * 66 + (gx + 1)) * CSL + slot;
            *(uint2*)hd = *(const uint2*)hv;
        }
    }
}

// ================= round-4 fallback (tiny ws) =================
constexpr int F_AROWB = 640;
constexpr int R4_ASLAB = 48 * 9 * KCH;
constexpr int R4_AVEC  = R4_ASLAB / 8;
constexpr int R4_ATOT  = 12 * R4_ASLAB;
constexpr int FPR = 10, FPC = 18;
__global__ void wconv_r4(const float* __restrict__ Wi, const float* __restrict__ Wh,
                         us* __restrict__ A2) {
    int idx = blockIdx.x * 256 + threadIdx.x;
    if (idx >= R4_ATOT) return;
    int ic = idx & 31; int r1 = idx >> 5;
    int tap = r1 % 9; int r2 = r1 / 9;
    int m = r2 & 15; int r3 = r2 >> 4;
    int gt = r3 % 3; int r4 = r3 / 3;
    int hg = r4 & 3; int ch = r4 >> 2;
    int o = gt * 64 + hg * 16 + m;
    float w = (ch == 0) ? Wi[(o * CIN + ic) * 9 + tap]
                        : Wh[(o * HID + (ch - 1) * 32 + ic) * 9 + tap];
    A2[idx] = f2bf(w);
}
__global__ __launch_bounds__(256, 2) void convgru_r4(
    const float* __restrict__ x, const us* __restrict__ A2,
    const float* hall, float* out, int t)
{
    __shared__ __align__(16) us tin[FPR * FPC * 40];
    __shared__ __align__(16) us Alr[48 * (F_AROWB / 2)];
    const int tid = threadIdx.x;
    const int lane = tid & 63, wave = tid >> 6;
    const int px = lane & 15, kl = lane >> 4;
    const int ty = blockIdx.x >> 2, tx = blockIdx.x & 3;
    const int hg = blockIdx.y, b = blockIdx.z;
    const int gy0 = ty * 8, gx0 = tx * 16;
    const int nch = (t > 0) ? 3 : 1;
    const float* hb = (t > 0) ? (hall + ((size_t)(b * T_ + t - 1)) * HID * HW) : nullptr;
    const float* xb = x + ((size_t)(b * T_ + t)) * CIN * HW;
    f32x4 accR[2] = {}, accZ[2] = {}, accNX[2] = {}, accNH[2] = {};
    float ireg[23]; bf16x8 areg[7];
    auto load_in = [&](int ch) {
        const float* src = (ch == 0) ? xb : (hb + (size_t)(ch - 1) * 32 * HW);
        #pragma unroll
        for (int j = 0; j < 23; ++j) {
            int e = tid + j * 256; float v = 0.f;
            if (e < FPR * FPC * 32) {
                int ic = e / (FPR * FPC); int rem = e - ic * (FPR * FPC);
                int r = rem / FPC, c = rem - r * FPC;
                int gy = gy0 + r - 1, gx = gx0 + c - 1;
                if ((unsigned)gy < (unsigned)HH && (unsigned)gx < (unsigned)WW)
                    v = src[ic * HW + gy * WW + gx];
            }
            ireg[j] = v;
        }
    };
    auto load_Ar = [&](int ch) {
        const us* s = A2 + (size_t)(ch * 4 + hg) * R4_ASLAB;
        #pragma unroll
        for (int j = 0; j < 7; ++j) { int v = tid + j * 256; if (v < R4_AVEC) areg[j] = *(const bf16x8*)(s + v * 8); }
    };
    auto write_in = [&]() {
        #pragma unroll
        for (int j = 0; j < 23; ++j) {
            int e = tid + j * 256;
            if (e < FPR * FPC * 32) {
                int ic = e / (FPR * FPC); int rem = e - ic * (FPR * FPC);
                int r = rem / FPC, c = rem - r * FPC;
                tin[(r * FPC + c) * 40 + ic] = f2bf(ireg[j]);
            }
        }
    };
    auto write_Ar = [&]() {
        #pragma unroll
        for (int j = 0; j < 7; ++j) {
            int v = tid + j * 256;
            if (v < R4_AVEC) {
                int row = v / 36; int kb = (v - row * 36) * 16;
                char* dst = (char*)Alr + row * F_AROWB + (kb ^ ((row & 7) << 4));
                *(bf16x8*)dst = areg[j];
            }
        }
    };
    const int rb0 = ((wave * 2 + 0) * FPC + px) * 40 + kl * 8;
    const int rb1 = rb0 + FPC * 40;
    const int swA = (px & 7) << 4;
    auto compute = [&](bool isX) {
        #pragma unroll
        for (int tap = 0; tap < 9; ++tap) {
            const int dy = tap / 3, dx = tap - 3 * dy;
            const int toff = (dy * FPC + dx) * 40;
            bf16x8 b0 = *(const bf16x8*)(tin + rb0 + toff);
            bf16x8 b1 = *(const bf16x8*)(tin + rb1 + toff);
            const char* ab = (const char*)Alr + px * F_AROWB + ((tap * 64 + kl * 16) ^ swA);
            bf16x8 ar = *(const bf16x8*)(ab);
            bf16x8 az = *(const bf16x8*)(ab + 16 * F_AROWB);
            bf16x8 an = *(const bf16x8*)(ab + 32 * F_AROWB);
            MFMA_B(accR[0], ar, b0); MFMA_B(accR[1], ar, b1);
            MFMA_B(accZ[0], az, b0); MFMA_B(accZ[1], az, b1);
            if (isX) { MFMA_B(accNX[0], an, b0); MFMA_B(accNX[1], an, b1); }
            else     { MFMA_B(accNH[0], an, b0); MFMA_B(accNH[1], an, b1); }
        }
    };
    load_in(0); load_Ar(0); write_in(); write_Ar();
    __syncthreads();
    for (int ch = 0; ch < nch; ++ch) {
        if (ch + 1 < nch) { load_in(ch + 1); load_Ar(ch + 1); }
        compute(ch == 0);
        __syncthreads();
        if (ch + 1 < nch) { write_in(); write_Ar(); __syncthreads(); }
    }
    float* outp = out + ((size_t)(b * T_ + t)) * HID * HW;
    #pragma unroll
    for (int g = 0; g < 2; ++g) {
        int gy = gy0 + wave * 2 + g; int gx = gx0 + px;
        #pragma unroll
        for (int q = 0; q < 4; ++q) {
            int c = hg * 16 + kl * 4 + q;
            float sr = 1.f / (1.f + expf(-accR[g][q]));
            float sz = 1.f / (1.f + expf(-accZ[g][q]));
            float nn = tanhf(accNX[g][q] + sr * accNH[g][q]);
            float hv = hb ? hb[(size_t)c * HW + gy * WW + gx] : 0.f;
            outp[(size_t)c * HW + gy * WW + gx] = (1.f - sz) * nn + sz * hv;
        }
    }
}

extern "C" void kernel_launch(void* const* d_in, const int* in_sizes, int n_in,
                              void* d_out, int out_size, void* d_ws, size_t ws_size,
                              hipStream_t stream) {
    const float* x  = (const float*)d_in[0];
    const float* Wi = (const float*)d_in[1];
    const float* Wh = (const float*)d_in[2];
    float* out = (float*)d_out;

    if (ws_size >= WS_NEED_BYTES) {
        us* A2  = (us*)d_ws;
        us* xT  = A2 + XT_OFF;
        us* hT0 = A2 + HT_OFF;
        us* hT1 = hT0 + HTBUF_HW;

        prep<<<PB_TOTAL, 256, 0, stream>>>(x, Wi, Wh, A2, xT, hT0);
        for (int t = 0; t < T_; ++t) {
            us* rd = (t & 1) ? hT1 : hT0;
            us* wr = (t & 1) ? hT0 : hT1;
            convgru_step<<<dim3(64, 1, 4), 256, 0, stream>>>(xT, A2, rd, wr, out, t);
        }
    } else {
        us* A2 = (us*)d_ws;
        wconv_r4<<<(R4_ATOT + 255) / 256, 256, 0, stream>>>(Wi, Wh, A2);
        for (int t = 0; t < T_; ++t)
            convgru_r4<<<dim3(32, 4, 4), 256, 0, stream>>>(x, A2, out, out, t);
    }
}